// Round 1
// baseline (1012.435 us; speedup 1.0000x reference)
//
#include <hip/hip_runtime.h>

#define N_ 16
#define C_ 512
#define S_ 1024
#define HEADS_ 8
#define HD_ 64
#define G_ 32
#define CPG_ 16
#define EPS_ 1e-6f

// ---------------- Kernel 1: GroupNorm ----------------
// One block per (n, g). Group data is contiguous: 16 channels x 1024 pixels.
__global__ __launch_bounds__(256) void gn_kernel(const float* __restrict__ x,
                                                 const float* __restrict__ scale,
                                                 const float* __restrict__ bias,
                                                 float* __restrict__ hn) {
    int blk = blockIdx.x;                 // n*G_ + g
    int tid = threadIdx.x;
    int g = blk & (G_ - 1);
    const float4* src4 = (const float4*)(x + (size_t)blk * (CPG_ * S_));
    float4* dst4 = (float4*)(hn + (size_t)blk * (CPG_ * S_));

    float s = 0.f, s2 = 0.f;
    for (int i = tid; i < 4096; i += 256) {
        float4 v = src4[i];
        s  += v.x + v.y + v.z + v.w;
        s2 += v.x*v.x + v.y*v.y + v.z*v.z + v.w*v.w;
    }
    __shared__ float red[256], red2[256];
    red[tid] = s; red2[tid] = s2;
    __syncthreads();
    for (int off = 128; off > 0; off >>= 1) {
        if (tid < off) { red[tid] += red[tid+off]; red2[tid] += red2[tid+off]; }
        __syncthreads();
    }
    __shared__ float mean_s, rstd_s;
    if (tid == 0) {
        float mean = red[0] * (1.f/16384.f);
        float var  = red2[0] * (1.f/16384.f) - mean*mean;
        mean_s = mean;
        rstd_s = rsqrtf(var + EPS_);
    }
    __syncthreads();
    float mean = mean_s, rstd = rstd_s;
    for (int i = tid; i < 4096; i += 256) {
        int c = g*CPG_ + (i >> 8);        // i/256 = channel within group
        float sc = scale[c] * rstd;
        float bi = bias[c] - mean * sc;
        float4 v = src4[i];
        v.x = v.x*sc + bi; v.y = v.y*sc + bi; v.z = v.z*sc + bi; v.w = v.w*sc + bi;
        dst4[i] = v;
    }
}

// ---------------- Kernel 2: QKV projection ----------------
// OUT[m][s] = sum_c W[c][m] * HN[c][s], per n. M=1536, K=512, Scols=1024.
// 128x128 block tile, 256 threads, 8x8 microtile (split 4+4), K-tile 8.
__global__ __launch_bounds__(256) void qkv_kernel(const float* __restrict__ hn,
        const float* __restrict__ w, const float* __restrict__ b,
        float* __restrict__ qb, float* __restrict__ kb, float* __restrict__ vb) {
    const int M = 3 * C_;                  // 1536
    int s0 = blockIdx.x * 128;
    int m0 = blockIdx.y * 128;
    int n  = blockIdx.z;
    const float* hnn = hn + (size_t)n * C_ * S_;

    __shared__ float At[8][132];
    __shared__ float Bt[8][132];
    int tid = threadIdx.x;
    int tx = tid & 15, ty = tid >> 4;
    int lr = tid >> 5;                     // 0..7
    int lc = (tid & 31) * 4;               // 0..124

    float acc[8][8];
    #pragma unroll
    for (int i = 0; i < 8; i++)
        #pragma unroll
        for (int j = 0; j < 8; j++) acc[i][j] = 0.f;

    for (int k0 = 0; k0 < C_; k0 += 8) {
        float4 av = *(const float4*)(w + (size_t)(k0 + lr) * M + m0 + lc);
        float4 bv = *(const float4*)(hnn + (size_t)(k0 + lr) * S_ + s0 + lc);
        __syncthreads();
        *(float4*)&At[lr][lc] = av;
        *(float4*)&Bt[lr][lc] = bv;
        __syncthreads();
        #pragma unroll
        for (int kk = 0; kk < 8; kk++) {
            float4 a0 = *(const float4*)&At[kk][ty*4];
            float4 a1 = *(const float4*)&At[kk][64 + ty*4];
            float4 b0 = *(const float4*)&Bt[kk][tx*4];
            float4 b1 = *(const float4*)&Bt[kk][64 + tx*4];
            float a[8] = {a0.x,a0.y,a0.z,a0.w,a1.x,a1.y,a1.z,a1.w};
            float bb[8] = {b0.x,b0.y,b0.z,b0.w,b1.x,b1.y,b1.z,b1.w};
            #pragma unroll
            for (int i = 0; i < 8; i++)
                #pragma unroll
                for (int j = 0; j < 8; j++) acc[i][j] += a[i]*bb[j];
        }
    }

    // Epilogue: scatter to q/k/v in [n][head][s][d] layout; fold 1/8 into q.
    #pragma unroll
    for (int rg = 0; rg < 2; rg++) {
        int m = m0 + rg*64 + ty*4;         // 4 consecutive d3
        int head = m / 192;
        int r = m - head*192;
        int which = r >> 6;
        int d0 = r & 63;
        float* base = (which == 0) ? qb : (which == 1) ? kb : vb;
        float scl = (which == 0) ? 0.125f : 1.0f;
        float4 bias = *(const float4*)(b + m);
        #pragma unroll
        for (int cg = 0; cg < 2; cg++) {
            #pragma unroll
            for (int j = 0; j < 4; j++) {
                int s = s0 + cg*64 + tx*4 + j;
                float4 o;
                o.x = (acc[rg*4+0][cg*4+j] + bias.x) * scl;
                o.y = (acc[rg*4+1][cg*4+j] + bias.y) * scl;
                o.z = (acc[rg*4+2][cg*4+j] + bias.z) * scl;
                o.w = (acc[rg*4+3][cg*4+j] + bias.w) * scl;
                *(float4*)(base + (((size_t)(n*HEADS_ + head)*S_ + s) << 6) + d0) = o;
            }
        }
    }
}

// ---------------- Kernel 3: flash attention ----------------
// Block = (query tile of 64) x (n,h). Online softmax. Q pre-scaled by 1/8.
__global__ __launch_bounds__(256) void attn_kernel(const float* __restrict__ qb,
        const float* __restrict__ kb, const float* __restrict__ vb,
        float* __restrict__ ao) {
    int qt = blockIdx.x;                   // 0..15
    int nh = blockIdx.y;                   // 0..127
    const float* Q = qb + (size_t)nh * S_ * HD_;
    const float* K = kb + (size_t)nh * S_ * HD_;
    const float* V = vb + (size_t)nh * S_ * HD_;

    __shared__ float Qt[64][68];           // [d][q]  (transposed)
    __shared__ float Kt[64][68];           // [d][t]  (transposed)
    __shared__ float Vt[64][68];           // [t][d]
    __shared__ float Pt[64][68];           // [t][q]
    __shared__ float mrow[64], lrow[64], arow[64];
    __shared__ float pmax[4][64], psum[4][64];

    int tid = threadIdx.x, tx = tid & 15, ty = tid >> 4;

    {   // load Q tile transposed
        int r = tid >> 2;
        int d0 = (tid & 3) * 16;
        const float* qp = Q + ((size_t)(qt*64 + r))*HD_ + d0;
        #pragma unroll
        for (int v4 = 0; v4 < 4; v4++) {
            float4 v = *(const float4*)(qp + v4*4);
            Qt[d0+v4*4+0][r] = v.x;
            Qt[d0+v4*4+1][r] = v.y;
            Qt[d0+v4*4+2][r] = v.z;
            Qt[d0+v4*4+3][r] = v.w;
        }
    }
    if (tid < 64) { mrow[tid] = -1e30f; lrow[tid] = 0.f; }
    float o[4][4];
    #pragma unroll
    for (int i = 0; i < 4; i++)
        #pragma unroll
        for (int j = 0; j < 4; j++) o[i][j] = 0.f;
    __syncthreads();

    for (int t0 = 0; t0 < S_; t0 += 64) {
        {   // stage K transposed, V natural
            int r = tid >> 2;
            int d0 = (tid & 3) * 16;
            const float* kp = K + ((size_t)(t0 + r))*HD_ + d0;
            const float* vp = V + ((size_t)(t0 + r))*HD_ + d0;
            #pragma unroll
            for (int v4 = 0; v4 < 4; v4++) {
                float4 kv = *(const float4*)(kp + v4*4);
                Kt[d0+v4*4+0][r] = kv.x;
                Kt[d0+v4*4+1][r] = kv.y;
                Kt[d0+v4*4+2][r] = kv.z;
                Kt[d0+v4*4+3][r] = kv.w;
                float4 vv = *(const float4*)(vp + v4*4);
                *(float4*)&Vt[r][d0 + v4*4] = vv;
            }
        }
        __syncthreads();

        // S = Q K^T  (q = ty*4+i, t = tx*4+j)
        float sacc[4][4];
        #pragma unroll
        for (int i = 0; i < 4; i++)
            #pragma unroll
            for (int j = 0; j < 4; j++) sacc[i][j] = 0.f;
        #pragma unroll 4
        for (int d = 0; d < 64; d++) {
            float4 a  = *(const float4*)&Qt[d][ty*4];
            float4 b4 = *(const float4*)&Kt[d][tx*4];
            float av[4] = {a.x,a.y,a.z,a.w};
            float bv[4] = {b4.x,b4.y,b4.z,b4.w};
            #pragma unroll
            for (int i = 0; i < 4; i++)
                #pragma unroll
                for (int j = 0; j < 4; j++) sacc[i][j] += av[i]*bv[j];
        }
        // write scores transposed: Pt[t][q]
        #pragma unroll
        for (int j = 0; j < 4; j++) {
            float4 v = {sacc[0][j], sacc[1][j], sacc[2][j], sacc[3][j]};
            *(float4*)&Pt[tx*4+j][ty*4] = v;
        }
        __syncthreads();

        {   // partial max: 4 threads per row
            int q = tid & 63, part = tid >> 6;
            float mx = -1e30f;
            #pragma unroll
            for (int t = part*16; t < part*16 + 16; t++) mx = fmaxf(mx, Pt[t][q]);
            pmax[part][q] = mx;
        }
        __syncthreads();
        if (tid < 64) {
            int q = tid;
            float mx = fmaxf(fmaxf(pmax[0][q], pmax[1][q]), fmaxf(pmax[2][q], pmax[3][q]));
            float mnew = fmaxf(mrow[q], mx);
            arow[q] = __expf(mrow[q] - mnew);
            mrow[q] = mnew;
        }
        __syncthreads();
        {   // exponentiate + partial sum
            int q = tid & 63, part = tid >> 6;
            float mnew = mrow[q];
            float sum = 0.f;
            #pragma unroll
            for (int t = part*16; t < part*16 + 16; t++) {
                float p = __expf(Pt[t][q] - mnew);
                Pt[t][q] = p;
                sum += p;
            }
            psum[part][q] = sum;
        }
        __syncthreads();
        if (tid < 64) {
            int q = tid;
            lrow[q] = lrow[q]*arow[q] + psum[0][q] + psum[1][q] + psum[2][q] + psum[3][q];
        }

        // rescale O and accumulate P·V  (q = ty*4+i, d = tx*4+j)
        float al[4];
        #pragma unroll
        for (int i = 0; i < 4; i++) al[i] = arow[ty*4+i];
        #pragma unroll
        for (int i = 0; i < 4; i++)
            #pragma unroll
            for (int j = 0; j < 4; j++) o[i][j] *= al[i];
        #pragma unroll 4
        for (int t = 0; t < 64; t++) {
            float4 a  = *(const float4*)&Pt[t][ty*4];
            float4 b4 = *(const float4*)&Vt[t][tx*4];
            float av[4] = {a.x,a.y,a.z,a.w};
            float bv[4] = {b4.x,b4.y,b4.z,b4.w};
            #pragma unroll
            for (int i = 0; i < 4; i++)
                #pragma unroll
                for (int j = 0; j < 4; j++) o[i][j] += av[i]*bv[j];
        }
        __syncthreads();
    }

    // write attnout [n][h*64+d][s], s = qt*64 + q (q contiguous along i)
    float li[4];
    #pragma unroll
    for (int i = 0; i < 4; i++) li[i] = 1.f / lrow[ty*4+i];
    #pragma unroll
    for (int j = 0; j < 4; j++) {
        int d = tx*4 + j;
        float4 v = {o[0][j]*li[0], o[1][j]*li[1], o[2][j]*li[2], o[3][j]*li[3]};
        *(float4*)(ao + ((size_t)(nh*64 + d))*S_ + qt*64 + ty*4) = v;
    }
}

// ---------------- Kernel 4: output projection + residual ----------------
// OUT[n][d][s] = x + b_out[d] + sum_c AO[n][c][s] * Wout[c][d]. M=512,K=512.
__global__ __launch_bounds__(256) void out_kernel(const float* __restrict__ ao,
        const float* __restrict__ w, const float* __restrict__ b,
        const float* __restrict__ x, float* __restrict__ out) {
    int s0 = blockIdx.x * 128;
    int m0 = blockIdx.y * 128;
    int n  = blockIdx.z;
    const float* aon = ao + (size_t)n * C_ * S_;
    const float* xn  = x  + (size_t)n * C_ * S_;
    float* outn      = out + (size_t)n * C_ * S_;

    __shared__ float At[8][132];
    __shared__ float Bt[8][132];
    int tid = threadIdx.x;
    int tx = tid & 15, ty = tid >> 4;
    int lr = tid >> 5;
    int lc = (tid & 31) * 4;

    float acc[8][8];
    #pragma unroll
    for (int i = 0; i < 8; i++)
        #pragma unroll
        for (int j = 0; j < 8; j++) acc[i][j] = 0.f;

    for (int k0 = 0; k0 < C_; k0 += 8) {
        float4 av = *(const float4*)(w + (size_t)(k0 + lr) * C_ + m0 + lc);
        float4 bv = *(const float4*)(aon + (size_t)(k0 + lr) * S_ + s0 + lc);
        __syncthreads();
        *(float4*)&At[lr][lc] = av;
        *(float4*)&Bt[lr][lc] = bv;
        __syncthreads();
        #pragma unroll
        for (int kk = 0; kk < 8; kk++) {
            float4 a0 = *(const float4*)&At[kk][ty*4];
            float4 a1 = *(const float4*)&At[kk][64 + ty*4];
            float4 b0 = *(const float4*)&Bt[kk][tx*4];
            float4 b1 = *(const float4*)&Bt[kk][64 + tx*4];
            float a[8] = {a0.x,a0.y,a0.z,a0.w,a1.x,a1.y,a1.z,a1.w};
            float bb[8] = {b0.x,b0.y,b0.z,b0.w,b1.x,b1.y,b1.z,b1.w};
            #pragma unroll
            for (int i = 0; i < 8; i++)
                #pragma unroll
                for (int j = 0; j < 8; j++) acc[i][j] += a[i]*bb[j];
        }
    }

    #pragma unroll
    for (int rg = 0; rg < 2; rg++) {
        #pragma unroll
        for (int i = 0; i < 4; i++) {
            int d = m0 + rg*64 + ty*4 + i;
            float bi = b[d];
            #pragma unroll
            for (int cg = 0; cg < 2; cg++) {
                int s = s0 + cg*64 + tx*4;
                size_t addr = (size_t)d * S_ + s;
                float4 xv = *(const float4*)(xn + addr);
                float4 o;
                o.x = acc[rg*4+i][cg*4+0] + bi + xv.x;
                o.y = acc[rg*4+i][cg*4+1] + bi + xv.y;
                o.z = acc[rg*4+i][cg*4+2] + bi + xv.z;
                o.w = acc[rg*4+i][cg*4+3] + bi + xv.w;
                *(float4*)(outn + addr) = o;
            }
        }
    }
}

extern "C" void kernel_launch(void* const* d_in, const int* in_sizes, int n_in,
                              void* d_out, int out_size, void* d_ws, size_t ws_size,
                              hipStream_t stream) {
    const float* x    = (const float*)d_in[0];
    const float* gns  = (const float*)d_in[1];
    const float* gnb  = (const float*)d_in[2];
    const float* wqkv = (const float*)d_in[3];
    const float* bqkv = (const float*)d_in[4];
    const float* wout = (const float*)d_in[5];
    const float* bout = (const float*)d_in[6];
    float* out = (float*)d_out;

    float* ws = (float*)d_ws;
    float* hn = ws;                        // 8.4M floats; reused as attn output
    float* q  = ws + 8388608;
    float* k  = ws + 16777216;
    float* v  = ws + 25165824;

    gn_kernel<<<dim3(N_ * G_), dim3(256), 0, stream>>>(x, gns, gnb, hn);
    qkv_kernel<<<dim3(8, 12, N_), dim3(256), 0, stream>>>(hn, wqkv, bqkv, q, k, v);
    attn_kernel<<<dim3(16, 128), dim3(256), 0, stream>>>(q, k, v, hn);
    out_kernel<<<dim3(8, 4, N_), dim3(256), 0, stream>>>(hn, wout, bout, x, out);
}

// Round 2
// 257.231 us; speedup vs baseline: 3.9359x; 3.9359x over previous
//
#include <hip/hip_runtime.h>
#include <stdint.h>

typedef __bf16 bf16x8 __attribute__((ext_vector_type(8)));
typedef float f32x4v __attribute__((ext_vector_type(4)));
typedef float f32x16v __attribute__((ext_vector_type(16)));

__device__ __forceinline__ unsigned short f2bf(float f) {
    unsigned u = __float_as_uint(f);
    u += 0x7fffu + ((u >> 16) & 1u);
    return (unsigned short)(u >> 16);
}

#define GLD_LDS16(gp, lp) __builtin_amdgcn_global_load_lds( \
    (const __attribute__((address_space(1))) unsigned int*)(gp), \
    (__attribute__((address_space(3))) unsigned int*)(lp), 16, 0, 0)

// ---------------- weight transpose fp32[R][Cc] -> bf16[Cc][R] ----------------
__global__ __launch_bounds__(256) void wt_kernel(const float* __restrict__ in,
        unsigned short* __restrict__ out, int R, int Cc) {
    __shared__ float tile[32][33];
    int c0 = blockIdx.x * 32, r0 = blockIdx.y * 32;
    int tx = threadIdx.x & 31, ty = threadIdx.x >> 5;
    #pragma unroll
    for (int i = 0; i < 4; i++) {
        int r = ty + i * 8;
        tile[r][tx] = in[(size_t)(r0 + r) * Cc + c0 + tx];
    }
    __syncthreads();
    #pragma unroll
    for (int i = 0; i < 4; i++) {
        int cr = ty + i * 8;
        out[(size_t)(c0 + cr) * R + r0 + tx] = f2bf(tile[tx][cr]);
    }
}

// ---------------- GroupNorm -> hnT bf16 [n][s][c] ----------------
__global__ __launch_bounds__(256) void gn_kernel(const float* __restrict__ x,
        const float* __restrict__ scale, const float* __restrict__ bias,
        unsigned short* __restrict__ hnT) {
    int blk = blockIdx.x;                  // n*32+g
    int tid = threadIdx.x;
    int g = blk & 31, n = blk >> 5;
    const float4* src4 = (const float4*)(x + (size_t)blk * 16384);

    float s = 0.f, s2 = 0.f;
    for (int i = tid; i < 4096; i += 256) {
        float4 v = src4[i];
        s  += v.x + v.y + v.z + v.w;
        s2 += v.x*v.x + v.y*v.y + v.z*v.z + v.w*v.w;
    }
    __shared__ float red[256], red2[256];
    red[tid] = s; red2[tid] = s2;
    __syncthreads();
    for (int off = 128; off > 0; off >>= 1) {
        if (tid < off) { red[tid] += red[tid+off]; red2[tid] += red2[tid+off]; }
        __syncthreads();
    }
    __shared__ float sc_s[16], bi_s[16];
    if (tid < 16) {
        float mean = red[0] * (1.f/16384.f);
        float var  = red2[0] * (1.f/16384.f) - mean*mean;
        float rstd = rsqrtf(var + 1e-6f);
        int c = g*16 + tid;
        float sc = scale[c] * rstd;
        sc_s[tid] = sc;
        bi_s[tid] = bias[c] - mean * sc;
    }
    __shared__ float tile[16][260];
    for (int ch = 0; ch < 4; ch++) {
        __syncthreads();
        #pragma unroll
        for (int kk = 0; kk < 4; kk++) {
            int fi = tid + kk*256;
            int row = fi >> 6, col4 = fi & 63;
            float4 v = src4[row*256 + ch*64 + col4];
            *(float4*)&tile[row][col4*4] = v;
        }
        __syncthreads();
        int sQ = ch*256 + tid;
        unsigned int pk[8];
        #pragma unroll
        for (int c2 = 0; c2 < 8; c2++) {
            float a = tile[c2*2][tid]   * sc_s[c2*2]   + bi_s[c2*2];
            float b = tile[c2*2+1][tid] * sc_s[c2*2+1] + bi_s[c2*2+1];
            pk[c2] = (unsigned)f2bf(a) | ((unsigned)f2bf(b) << 16);
        }
        unsigned short* op = hnT + ((size_t)(n*1024 + sQ))*512 + g*16;
        *(uint4*)op       = make_uint4(pk[0], pk[1], pk[2], pk[3]);
        *((uint4*)op + 1) = make_uint4(pk[4], pk[5], pk[6], pk[7]);
    }
}

// ---------------- QKV GEMM: D[m][s] = sum_c WqT[m][c]*hnT[s][c] ----------------
__global__ __launch_bounds__(256) void qkv_kernel(
        const unsigned short* __restrict__ WqT, const unsigned short* __restrict__ hnT,
        const float* __restrict__ bqkv,
        unsigned short* __restrict__ qb, unsigned short* __restrict__ kbuf,
        unsigned short* __restrict__ vb) {
    int s0 = blockIdx.x * 128, m0 = blockIdx.y * 128, n = blockIdx.z;
    __shared__ unsigned short At[4096];    // 128 rows x 32 c, swizzled 16B chunks
    __shared__ unsigned short Bt[4096];
    int tid = threadIdx.x;
    int lane = tid & 63, w = tid >> 6;
    int quad = lane >> 4, tx = lane & 15;
    int moff = (w & 1) * 64, soff = (w >> 1) * 64;

    const unsigned short* Arow = WqT + (size_t)m0 * 512;
    const unsigned short* Brow = hnT + ((size_t)n * 1024 + s0) * 512;

    f32x4v acc[4][4];
    #pragma unroll
    for (int i = 0; i < 4; i++)
        #pragma unroll
        for (int j = 0; j < 4; j++)
            #pragma unroll
            for (int e = 0; e < 4; e++) acc[i][j][e] = 0.f;

    int f1 = tid, f2 = tid + 256;
    int m1 = f1 >> 2, kb1 = ((f1 & 3) - (f1 >> 3)) & 3;
    int m2 = f2 >> 2, kb2 = ((f2 & 3) - (f2 >> 3)) & 3;

    for (int k0 = 0; k0 < 512; k0 += 32) {
        __syncthreads();
        GLD_LDS16(Arow + (size_t)m1*512 + k0 + kb1*8, At + f1*8);
        GLD_LDS16(Arow + (size_t)m2*512 + k0 + kb2*8, At + f2*8);
        GLD_LDS16(Brow + (size_t)m1*512 + k0 + kb1*8, Bt + f1*8);
        GLD_LDS16(Brow + (size_t)m2*512 + k0 + kb2*8, Bt + f2*8);
        __syncthreads();
        bf16x8 af[4], bfr[4];
        #pragma unroll
        for (int mt = 0; mt < 4; mt++) {
            int m = moff + mt*16 + tx;
            int ch = m*4 + ((quad + (m >> 1)) & 3);
            af[mt] = *(const bf16x8*)(At + ch*8);
        }
        #pragma unroll
        for (int nt = 0; nt < 4; nt++) {
            int m = soff + nt*16 + tx;
            int ch = m*4 + ((quad + (m >> 1)) & 3);
            bfr[nt] = *(const bf16x8*)(Bt + ch*8);
        }
        #pragma unroll
        for (int mt = 0; mt < 4; mt++)
            #pragma unroll
            for (int nt = 0; nt < 4; nt++)
                acc[mt][nt] = __builtin_amdgcn_mfma_f32_16x16x32_bf16(
                    af[mt], bfr[nt], acc[mt][nt], 0, 0, 0);
    }

    #pragma unroll
    for (int mt = 0; mt < 4; mt++) {
        int m = m0 + moff + mt*16 + quad*4;
        int head = m / 192;
        int r = m - head*192;
        int which = r >> 6;
        int d0 = r & 63;
        float4 bia = *(const float4*)(bqkv + m);
        float scl = (which == 0) ? 0.125f : 1.0f;
        #pragma unroll
        for (int nt = 0; nt < 4; nt++) {
            int sQ = s0 + soff + nt*16 + tx;
            f32x4v a = acc[mt][nt];
            float v0 = (a[0]+bia.x)*scl, v1 = (a[1]+bia.y)*scl;
            float v2 = (a[2]+bia.z)*scl, v3 = (a[3]+bia.w)*scl;
            if (which < 2) {
                unsigned short* base = (which == 0) ? qb : kbuf;
                ushort4 pkv;
                pkv.x = f2bf(v0); pkv.y = f2bf(v1); pkv.z = f2bf(v2); pkv.w = f2bf(v3);
                *(ushort4*)(base + (((size_t)(n*8 + head)*1024 + sQ) << 6) + d0) = pkv;
            } else {
                size_t vbase = ((size_t)(n*8 + head)*64 + d0)*1024 + sQ;
                vb[vbase]        = f2bf(v0);
                vb[vbase + 1024] = f2bf(v1);
                vb[vbase + 2048] = f2bf(v2);
                vb[vbase + 3072] = f2bf(v3);
            }
        }
    }
}

// ---------------- flash attention, 32x32x16 MFMA, S^T = K Q^T ----------------
__global__ __launch_bounds__(256) void attn_kernel(
        const unsigned short* __restrict__ qg, const unsigned short* __restrict__ kg,
        const unsigned short* __restrict__ vg, unsigned short* __restrict__ ao) {
    int qbk = blockIdx.x, nh = blockIdx.y;
    int tid = threadIdx.x, w = tid >> 6, lane = tid & 63;
    int lq = lane & 31, hi = lane >> 5;
    const unsigned short* Q = qg + (size_t)nh * 65536;
    const unsigned short* K = kg + (size_t)nh * 65536;
    const unsigned short* V = vg + (size_t)nh * 65536;   // [d][t]

    __shared__ unsigned short Klds[64*72];               // [t][d], pad 8
    __shared__ unsigned short Vlds[64*72];               // [d][t], pad 8
    __shared__ unsigned short Plds[4][32*72];            // per-wave [q][t]
    __shared__ float alpha_s[4][32];
    __shared__ float lsum_s[4][32];

    int q0 = qbk*128 + w*32;
    bf16x8 qf[4];
    #pragma unroll
    for (int ks = 0; ks < 4; ks++)
        qf[ks] = *(const bf16x8*)(Q + ((size_t)(q0 + lq))*64 + ks*16 + hi*8);

    f32x16v O0, O1;
    #pragma unroll
    for (int i = 0; i < 16; i++) { O0[i] = 0.f; O1[i] = 0.f; }
    float mrun = -1e30f, lrun = 0.f;

    for (int t0 = 0; t0 < 1024; t0 += 64) {
        __syncthreads();
        {
            int r = tid >> 2, part = tid & 3;
            const float4* kp = (const float4*)(K + ((size_t)(t0 + r))*64 + part*16);
            float4 a = kp[0], b = kp[1];
            *(float4*)&Klds[r*72 + part*16]     = a;
            *(float4*)&Klds[r*72 + part*16 + 8] = b;
            const float4* vp = (const float4*)(V + (size_t)r*1024 + t0 + part*16);
            float4 c = vp[0], d = vp[1];
            *(float4*)&Vlds[r*72 + part*16]     = c;
            *(float4*)&Vlds[r*72 + part*16 + 8] = d;
        }
        __syncthreads();

        f32x16v S0, S1;
        #pragma unroll
        for (int i = 0; i < 16; i++) { S0[i] = 0.f; S1[i] = 0.f; }
        #pragma unroll
        for (int ks = 0; ks < 4; ks++) {
            bf16x8 a0 = *(const bf16x8*)(Klds + lq*72 + ks*16 + hi*8);
            bf16x8 a1 = *(const bf16x8*)(Klds + (32+lq)*72 + ks*16 + hi*8);
            S0 = __builtin_amdgcn_mfma_f32_32x32x16_bf16(a0, qf[ks], S0, 0, 0, 0);
            S1 = __builtin_amdgcn_mfma_f32_32x32x16_bf16(a1, qf[ks], S1, 0, 0, 0);
        }

        float mx = -1e30f;
        #pragma unroll
        for (int i = 0; i < 16; i++) mx = fmaxf(mx, fmaxf(S0[i], S1[i]));
        mx = fmaxf(mx, __shfl_xor(mx, 32));
        float mnew = fmaxf(mrun, mx);
        float alpha = __expf(mrun - mnew);
        mrun = mnew;
        float p0[16], p1[16], sum = 0.f;
        #pragma unroll
        for (int i = 0; i < 16; i++) {
            p0[i] = __expf(S0[i] - mnew);
            p1[i] = __expf(S1[i] - mnew);
            sum += p0[i] + p1[i];
        }
        sum += __shfl_xor(sum, 32);
        lrun = lrun * alpha + sum;
        alpha_s[w][lq] = alpha;

        unsigned short* Pw = Plds[w];
        #pragma unroll
        for (int rq = 0; rq < 4; rq++) {
            ushort4 pa, pb;
            pa.x = f2bf(p0[rq*4+0]); pa.y = f2bf(p0[rq*4+1]);
            pa.z = f2bf(p0[rq*4+2]); pa.w = f2bf(p0[rq*4+3]);
            pb.x = f2bf(p1[rq*4+0]); pb.y = f2bf(p1[rq*4+1]);
            pb.z = f2bf(p1[rq*4+2]); pb.w = f2bf(p1[rq*4+3]);
            *(ushort4*)(Pw + lq*72 + rq*8 + hi*4)      = pa;   // t-rows of S0
            *(ushort4*)(Pw + lq*72 + 32 + rq*8 + hi*4) = pb;   // t-rows of S1
        }

        #pragma unroll
        for (int rq = 0; rq < 4; rq++) {
            float4 av = *(const float4*)&alpha_s[w][rq*8 + hi*4];
            O0[rq*4+0] *= av.x; O0[rq*4+1] *= av.y; O0[rq*4+2] *= av.z; O0[rq*4+3] *= av.w;
            O1[rq*4+0] *= av.x; O1[rq*4+1] *= av.y; O1[rq*4+2] *= av.z; O1[rq*4+3] *= av.w;
        }
        #pragma unroll
        for (int ks = 0; ks < 4; ks++) {
            bf16x8 pa = *(const bf16x8*)(Pw + lq*72 + ks*16 + hi*8);
            bf16x8 v0 = *(const bf16x8*)(Vlds + lq*72 + ks*16 + hi*8);
            bf16x8 v1 = *(const bf16x8*)(Vlds + (32+lq)*72 + ks*16 + hi*8);
            O0 = __builtin_amdgcn_mfma_f32_32x32x16_bf16(pa, v0, O0, 0, 0, 0);
            O1 = __builtin_amdgcn_mfma_f32_32x32x16_bf16(pa, v1, O1, 0, 0, 0);
        }
    }

    lsum_s[w][lq] = lrun;
    int n = nh >> 3, h = nh & 7;
    #pragma unroll
    for (int rq = 0; rq < 4; rq++) {
        float4 lv = *(const float4*)&lsum_s[w][rq*8 + hi*4];
        float inv0 = 1.f/lv.x, inv1 = 1.f/lv.y, inv2 = 1.f/lv.z, inv3 = 1.f/lv.w;
        float invs[4] = {inv0, inv1, inv2, inv3};
        #pragma unroll
        for (int i = 0; i < 4; i++) {
            int sQ = q0 + rq*8 + hi*4 + i;
            size_t rowb = ((size_t)(n*1024 + sQ))*512 + h*64;
            ao[rowb + lq]      = f2bf(O0[rq*4+i] * invs[i]);
            ao[rowb + 32 + lq] = f2bf(O1[rq*4+i] * invs[i]);
        }
    }
}

// ---------------- out GEMM: D[s][d] = sum_c aoT[s][c]*WoT[d][c]; +bias+x ----------------
__global__ __launch_bounds__(256) void out_kernel(
        const unsigned short* __restrict__ aoT, const unsigned short* __restrict__ WoT,
        const float* __restrict__ bout, const float* __restrict__ x,
        float* __restrict__ out) {
    int s0 = blockIdx.x * 128, d0b = blockIdx.y * 128, n = blockIdx.z;
    __shared__ unsigned short At[4096];
    __shared__ unsigned short Bt[4096];
    int tid = threadIdx.x;
    int lane = tid & 63, w = tid >> 6;
    int quad = lane >> 4, tx = lane & 15;
    int moff = (w & 1) * 64, noff = (w >> 1) * 64;

    const unsigned short* Arow = aoT + ((size_t)n * 1024 + s0) * 512;
    const unsigned short* Brow = WoT + (size_t)d0b * 512;

    f32x4v acc[4][4];
    #pragma unroll
    for (int i = 0; i < 4; i++)
        #pragma unroll
        for (int j = 0; j < 4; j++)
            #pragma unroll
            for (int e = 0; e < 4; e++) acc[i][j][e] = 0.f;

    int f1 = tid, f2 = tid + 256;
    int m1 = f1 >> 2, kb1 = ((f1 & 3) - (f1 >> 3)) & 3;
    int m2 = f2 >> 2, kb2 = ((f2 & 3) - (f2 >> 3)) & 3;

    for (int k0 = 0; k0 < 512; k0 += 32) {
        __syncthreads();
        GLD_LDS16(Arow + (size_t)m1*512 + k0 + kb1*8, At + f1*8);
        GLD_LDS16(Arow + (size_t)m2*512 + k0 + kb2*8, At + f2*8);
        GLD_LDS16(Brow + (size_t)m1*512 + k0 + kb1*8, Bt + f1*8);
        GLD_LDS16(Brow + (size_t)m2*512 + k0 + kb2*8, Bt + f2*8);
        __syncthreads();
        bf16x8 af[4], bfr[4];
        #pragma unroll
        for (int mt = 0; mt < 4; mt++) {
            int m = moff + mt*16 + tx;
            int ch = m*4 + ((quad + (m >> 1)) & 3);
            af[mt] = *(const bf16x8*)(At + ch*8);
        }
        #pragma unroll
        for (int nt = 0; nt < 4; nt++) {
            int m = noff + nt*16 + tx;
            int ch = m*4 + ((quad + (m >> 1)) & 3);
            bfr[nt] = *(const bf16x8*)(Bt + ch*8);
        }
        #pragma unroll
        for (int mt = 0; mt < 4; mt++)
            #pragma unroll
            for (int nt = 0; nt < 4; nt++)
                acc[mt][nt] = __builtin_amdgcn_mfma_f32_16x16x32_bf16(
                    af[mt], bfr[nt], acc[mt][nt], 0, 0, 0);
    }

    #pragma unroll
    for (int mt = 0; mt < 4; mt++) {
        int sQ = s0 + moff + mt*16 + quad*4;
        #pragma unroll
        for (int nt = 0; nt < 4; nt++) {
            int d = d0b + noff + nt*16 + tx;
            float bo = bout[d];
            size_t base = ((size_t)n*512 + d)*1024 + sQ;
            float4 xv = *(const float4*)(x + base);
            f32x4v a = acc[mt][nt];
            float4 o = make_float4(a[0]+bo+xv.x, a[1]+bo+xv.y, a[2]+bo+xv.z, a[3]+bo+xv.w);
            *(float4*)(out + base) = o;
        }
    }
}

extern "C" void kernel_launch(void* const* d_in, const int* in_sizes, int n_in,
                              void* d_out, int out_size, void* d_ws, size_t ws_size,
                              hipStream_t stream) {
    const float* x    = (const float*)d_in[0];
    const float* gns  = (const float*)d_in[1];
    const float* gnb  = (const float*)d_in[2];
    const float* wqkv = (const float*)d_in[3];
    const float* bqkv = (const float*)d_in[4];
    const float* wout = (const float*)d_in[5];
    const float* bout = (const float*)d_in[6];
    float* out = (float*)d_out;

    char* p = (char*)d_ws;
    size_t off = 0;
    auto carve = [&](size_t bytes) {
        char* r = p + off;
        off = (off + bytes + 255) & ~(size_t)255;
        return r;
    };
    unsigned short* hnT = (unsigned short*)carve((size_t)16*1024*512*2);
    unsigned short* qb2 = (unsigned short*)carve((size_t)128*1024*64*2);
    unsigned short* kb2 = (unsigned short*)carve((size_t)128*1024*64*2);
    unsigned short* vb2 = (unsigned short*)carve((size_t)128*64*1024*2);
    unsigned short* aoT = (unsigned short*)carve((size_t)16*1024*512*2);
    unsigned short* WqT = (unsigned short*)carve((size_t)1536*512*2);
    unsigned short* WoT = (unsigned short*)carve((size_t)512*512*2);

    wt_kernel<<<dim3(48, 16), 256, 0, stream>>>(wqkv, WqT, 512, 1536);
    wt_kernel<<<dim3(16, 16), 256, 0, stream>>>(wout, WoT, 512, 512);
    gn_kernel<<<dim3(512), 256, 0, stream>>>(x, gns, gnb, hnT);
    qkv_kernel<<<dim3(8, 12, 16), 256, 0, stream>>>(WqT, hnT, bqkv, qb2, kb2, vb2);
    attn_kernel<<<dim3(8, 128), 256, 0, stream>>>(qb2, kb2, vb2, aoT);
    out_kernel<<<dim3(8, 4, 16), 256, 0, stream>>>(aoT, WoT, bout, x, out);
}

// Round 3
// 248.061 us; speedup vs baseline: 4.0814x; 1.0370x over previous
//
#include <hip/hip_runtime.h>
#include <stdint.h>

typedef __bf16 bf16x8 __attribute__((ext_vector_type(8)));
typedef float f32x4v __attribute__((ext_vector_type(4)));
typedef float f32x16v __attribute__((ext_vector_type(16)));

// round-to-nearest bf16 (2 ops)
__device__ __forceinline__ unsigned f2bf_rn(float f) {
    return (__float_as_uint(f) + 0x8000u) >> 16;
}
// pack two floats -> two bf16 in one dword: 2 adds + 1 v_perm
__device__ __forceinline__ unsigned pk2bf(float a, float b) {
    return __builtin_amdgcn_perm(__float_as_uint(b) + 0x8000u,
                                 __float_as_uint(a) + 0x8000u, 0x07060302u);
}

#define GLD_LDS16(gp, lp) __builtin_amdgcn_global_load_lds( \
    (const __attribute__((address_space(1))) unsigned int*)(gp), \
    (__attribute__((address_space(3))) unsigned int*)(lp), 16, 0, 0)

// ---------------- weight transposes (both matrices, one launch) ----------------
__global__ __launch_bounds__(256) void wt_kernel(const float* __restrict__ wqkv,
        const float* __restrict__ wout, unsigned short* __restrict__ WqT,
        unsigned short* __restrict__ WoT) {
    __shared__ float tile[32][33];
    int bx = blockIdx.x;
    const float* in; unsigned short* out; int Cc, c0;
    if (bx < 48) { in = wqkv; out = WqT; Cc = 1536; c0 = bx * 32; }
    else         { in = wout; out = WoT; Cc = 512;  c0 = (bx - 48) * 32; }
    int r0 = blockIdx.y * 32;
    int tx = threadIdx.x & 31, ty = threadIdx.x >> 5;
    #pragma unroll
    for (int i = 0; i < 4; i++) {
        int r = ty + i * 8;
        tile[r][tx] = in[(size_t)(r0 + r) * Cc + c0 + tx];
    }
    __syncthreads();
    #pragma unroll
    for (int i = 0; i < 4; i++) {
        int cr = ty + i * 8;
        out[(size_t)(c0 + cr) * 512 + r0 + tx] = (unsigned short)f2bf_rn(tile[tx][cr]);
    }
}

// ---------------- GroupNorm -> hnT bf16 [n][s][c] ----------------
__global__ __launch_bounds__(256) void gn_kernel(const float* __restrict__ x,
        const float* __restrict__ scale, const float* __restrict__ bias,
        unsigned short* __restrict__ hnT) {
    int blk = blockIdx.x;                  // n*32+g
    int tid = threadIdx.x;
    int g = blk & 31, n = blk >> 5;
    const float4* src4 = (const float4*)(x + (size_t)blk * 16384);

    float s = 0.f, s2 = 0.f;
    for (int i = tid; i < 4096; i += 256) {
        float4 v = src4[i];
        s  += v.x + v.y + v.z + v.w;
        s2 += v.x*v.x + v.y*v.y + v.z*v.z + v.w*v.w;
    }
    __shared__ float red[256], red2[256];
    red[tid] = s; red2[tid] = s2;
    __syncthreads();
    for (int off = 128; off > 0; off >>= 1) {
        if (tid < off) { red[tid] += red[tid+off]; red2[tid] += red2[tid+off]; }
        __syncthreads();
    }
    __shared__ float sc_s[16], bi_s[16];
    if (tid < 16) {
        float mean = red[0] * (1.f/16384.f);
        float var  = red2[0] * (1.f/16384.f) - mean*mean;
        float rstd = rsqrtf(var + 1e-6f);
        int c = g*16 + tid;
        float sc = scale[c] * rstd;
        sc_s[tid] = sc;
        bi_s[tid] = bias[c] - mean * sc;
    }
    __shared__ float tile[16][260];
    for (int ch = 0; ch < 4; ch++) {
        __syncthreads();
        #pragma unroll
        for (int kk = 0; kk < 4; kk++) {
            int fi = tid + kk*256;
            int row = fi >> 6, col4 = fi & 63;
            float4 v = src4[row*256 + ch*64 + col4];
            *(float4*)&tile[row][col4*4] = v;
        }
        __syncthreads();
        int sQ = ch*256 + tid;
        unsigned int pk[8];
        #pragma unroll
        for (int c2 = 0; c2 < 8; c2++) {
            float a = tile[c2*2][tid]   * sc_s[c2*2]   + bi_s[c2*2];
            float b = tile[c2*2+1][tid] * sc_s[c2*2+1] + bi_s[c2*2+1];
            pk[c2] = pk2bf(a, b);
        }
        unsigned short* op = hnT + ((size_t)(n*1024 + sQ))*512 + g*16;
        *(uint4*)op       = make_uint4(pk[0], pk[1], pk[2], pk[3]);
        *((uint4*)op + 1) = make_uint4(pk[4], pk[5], pk[6], pk[7]);
    }
}

// ---------------- QKV GEMM: D[m][s] = sum_c WqT[m][c]*hnT[s][c] ----------------
__global__ __launch_bounds__(256) void qkv_kernel(
        const unsigned short* __restrict__ WqT, const unsigned short* __restrict__ hnT,
        const float* __restrict__ bqkv,
        unsigned short* __restrict__ qb, unsigned short* __restrict__ kbuf,
        unsigned short* __restrict__ vb) {
    int s0 = blockIdx.x * 128, m0 = blockIdx.y * 128, n = blockIdx.z;
    __shared__ unsigned short At[4096];    // 128 rows x 32 c, swizzled 16B chunks
    __shared__ unsigned short Bt[4096];
    int tid = threadIdx.x;
    int lane = tid & 63, w = tid >> 6;
    int quad = lane >> 4, tx = lane & 15;
    int moff = (w & 1) * 64, soff = (w >> 1) * 64;

    const unsigned short* Arow = WqT + (size_t)m0 * 512;
    const unsigned short* Brow = hnT + ((size_t)n * 1024 + s0) * 512;

    f32x4v acc[4][4];
    #pragma unroll
    for (int i = 0; i < 4; i++)
        #pragma unroll
        for (int j = 0; j < 4; j++)
            #pragma unroll
            for (int e = 0; e < 4; e++) acc[i][j][e] = 0.f;

    int f1 = tid, f2 = tid + 256;
    int m1 = f1 >> 2, kb1 = ((f1 & 3) - (f1 >> 3)) & 3;
    int m2 = f2 >> 2, kb2 = ((f2 & 3) - (f2 >> 3)) & 3;

    for (int k0 = 0; k0 < 512; k0 += 32) {
        __syncthreads();
        GLD_LDS16(Arow + (size_t)m1*512 + k0 + kb1*8, At + f1*8);
        GLD_LDS16(Arow + (size_t)m2*512 + k0 + kb2*8, At + f2*8);
        GLD_LDS16(Brow + (size_t)m1*512 + k0 + kb1*8, Bt + f1*8);
        GLD_LDS16(Brow + (size_t)m2*512 + k0 + kb2*8, Bt + f2*8);
        __syncthreads();
        bf16x8 af[4], bfr[4];
        #pragma unroll
        for (int mt = 0; mt < 4; mt++) {
            int m = moff + mt*16 + tx;
            int ch = m*4 + ((quad + (m >> 1)) & 3);
            af[mt] = *(const bf16x8*)(At + ch*8);
        }
        #pragma unroll
        for (int nt = 0; nt < 4; nt++) {
            int m = soff + nt*16 + tx;
            int ch = m*4 + ((quad + (m >> 1)) & 3);
            bfr[nt] = *(const bf16x8*)(Bt + ch*8);
        }
        #pragma unroll
        for (int mt = 0; mt < 4; mt++)
            #pragma unroll
            for (int nt = 0; nt < 4; nt++)
                acc[mt][nt] = __builtin_amdgcn_mfma_f32_16x16x32_bf16(
                    af[mt], bfr[nt], acc[mt][nt], 0, 0, 0);
    }

    // Epilogue: q scaled by 0.125*log2(e) (exp2-domain softmax downstream).
    const float QSCL = 0.18033688011112042f;
    #pragma unroll
    for (int mt = 0; mt < 4; mt++) {
        int m = m0 + moff + mt*16 + quad*4;
        int head = m / 192;
        int r = m - head*192;
        int which = r >> 6;
        int d0 = r & 63;
        float4 bia = *(const float4*)(bqkv + m);
        float scl = (which == 0) ? QSCL : 1.0f;
        #pragma unroll
        for (int nt = 0; nt < 4; nt++) {
            int sQ = s0 + soff + nt*16 + tx;
            f32x4v a = acc[mt][nt];
            float v0 = (a[0]+bia.x)*scl, v1 = (a[1]+bia.y)*scl;
            float v2 = (a[2]+bia.z)*scl, v3 = (a[3]+bia.w)*scl;
            if (which < 2) {
                unsigned short* base = (which == 0) ? qb : kbuf;
                unsigned lo = pk2bf(v0, v1), hi2 = pk2bf(v2, v3);
                *(uint2*)(base + (((size_t)(n*8 + head)*1024 + sQ) << 6) + d0) =
                    make_uint2(lo, hi2);
            } else {
                size_t vbase = ((size_t)(n*8 + head)*64 + d0)*1024 + sQ;
                vb[vbase]        = (unsigned short)f2bf_rn(v0);
                vb[vbase + 1024] = (unsigned short)f2bf_rn(v1);
                vb[vbase + 2048] = (unsigned short)f2bf_rn(v2);
                vb[vbase + 3072] = (unsigned short)f2bf_rn(v3);
            }
        }
    }
}

// ---------------- flash attention, BK=128, exp2-domain softmax ----------------
__global__ __launch_bounds__(256) void attn_kernel(
        const unsigned short* __restrict__ qg, const unsigned short* __restrict__ kg,
        const unsigned short* __restrict__ vg, unsigned short* __restrict__ ao) {
    int bid = blockIdx.x;
    int nh = bid & 127, qbk = bid >> 7;     // 8 q-blocks of one head share an XCD
    int tid = threadIdx.x, w = tid >> 6, lane = tid & 63;
    int lq = lane & 31, hi = lane >> 5;
    const unsigned short* Q = qg + (size_t)nh * 65536;
    const unsigned short* K = kg + (size_t)nh * 65536;
    const unsigned short* V = vg + (size_t)nh * 65536;   // [d][t]

    __shared__ unsigned short Klds[128*72];              // [t][d], pad 8
    __shared__ unsigned short Vlds[64*136];              // [d][t(128)], pad 8
    __shared__ unsigned short Plds[4][32*136];           // per-wave [q][t(128)]
    __shared__ float alpha_s[4][32];
    __shared__ float lsum_s[4][32];

    int q0 = qbk*128 + w*32;
    bf16x8 qf[4];
    #pragma unroll
    for (int ks = 0; ks < 4; ks++)
        qf[ks] = *(const bf16x8*)(Q + ((size_t)(q0 + lq))*64 + ks*16 + hi*8);

    f32x16v O0, O1;
    #pragma unroll
    for (int i = 0; i < 16; i++) { O0[i] = 0.f; O1[i] = 0.f; }
    float mrun = -1e30f, lrun = 0.f;

    for (int t0 = 0; t0 < 1024; t0 += 128) {
        __syncthreads();
        {   // stage K [128][64] and V [64][128]
            int r = tid >> 1, part = (tid & 1) * 32;
            const uint4* kp = (const uint4*)(K + (size_t)(t0 + r)*64 + part);
            uint4 a = kp[0], b = kp[1], c = kp[2], d = kp[3];
            unsigned short* kd = Klds + r*72 + part;
            *(uint4*)kd = a; *(uint4*)(kd+8) = b; *(uint4*)(kd+16) = c; *(uint4*)(kd+24) = d;
            int vr = tid >> 2, vpart = (tid & 3) * 32;
            const uint4* vp = (const uint4*)(V + (size_t)vr*1024 + t0 + vpart);
            uint4 e = vp[0], f = vp[1], g2 = vp[2], h2 = vp[3];
            unsigned short* vd = Vlds + vr*136 + vpart;
            *(uint4*)vd = e; *(uint4*)(vd+8) = f; *(uint4*)(vd+16) = g2; *(uint4*)(vd+24) = h2;
        }
        __syncthreads();

        f32x16v S[4];
        #pragma unroll
        for (int b = 0; b < 4; b++)
            #pragma unroll
            for (int i = 0; i < 16; i++) S[b][i] = 0.f;
        #pragma unroll
        for (int ks = 0; ks < 4; ks++) {
            #pragma unroll
            for (int b = 0; b < 4; b++) {
                bf16x8 a = *(const bf16x8*)(Klds + (b*32 + lq)*72 + ks*16 + hi*8);
                S[b] = __builtin_amdgcn_mfma_f32_32x32x16_bf16(a, qf[ks], S[b], 0, 0, 0);
            }
        }

        float mx = -1e30f;
        #pragma unroll
        for (int b = 0; b < 4; b++)
            #pragma unroll
            for (int i = 0; i < 16; i++) mx = fmaxf(mx, S[b][i]);
        mx = fmaxf(mx, __shfl_xor(mx, 32));
        float mnew = fmaxf(mrun, mx);
        float alpha = exp2f(mrun - mnew);
        mrun = mnew;
        float sum = 0.f;
        #pragma unroll
        for (int b = 0; b < 4; b++)
            #pragma unroll
            for (int i = 0; i < 16; i++) {
                float p = exp2f(S[b][i] - mnew);
                S[b][i] = p;
                sum += p;
            }
        sum += __shfl_xor(sum, 32);
        lrun = lrun * alpha + sum;
        alpha_s[w][lq] = alpha;

        unsigned short* Pw = Plds[w];
        #pragma unroll
        for (int b = 0; b < 4; b++)
            #pragma unroll
            for (int rq = 0; rq < 4; rq++) {
                unsigned lo  = pk2bf(S[b][rq*4+0], S[b][rq*4+1]);
                unsigned hi2 = pk2bf(S[b][rq*4+2], S[b][rq*4+3]);
                *(uint2*)(Pw + lq*136 + b*32 + rq*8 + hi*4) = make_uint2(lo, hi2);
            }

        #pragma unroll
        for (int rq = 0; rq < 4; rq++) {
            float4 av = *(const float4*)&alpha_s[w][rq*8 + hi*4];
            O0[rq*4+0] *= av.x; O0[rq*4+1] *= av.y; O0[rq*4+2] *= av.z; O0[rq*4+3] *= av.w;
            O1[rq*4+0] *= av.x; O1[rq*4+1] *= av.y; O1[rq*4+2] *= av.z; O1[rq*4+3] *= av.w;
        }
        #pragma unroll
        for (int ks = 0; ks < 8; ks++) {
            bf16x8 pa = *(const bf16x8*)(Pw + lq*136 + ks*16 + hi*8);
            bf16x8 v0 = *(const bf16x8*)(Vlds + lq*136 + ks*16 + hi*8);
            bf16x8 v1 = *(const bf16x8*)(Vlds + (32+lq)*136 + ks*16 + hi*8);
            O0 = __builtin_amdgcn_mfma_f32_32x32x16_bf16(pa, v0, O0, 0, 0, 0);
            O1 = __builtin_amdgcn_mfma_f32_32x32x16_bf16(pa, v1, O1, 0, 0, 0);
        }
    }

    lsum_s[w][lq] = lrun;
    int n = nh >> 3, h = nh & 7;
    #pragma unroll
    for (int rq = 0; rq < 4; rq++) {
        float4 lv = *(const float4*)&lsum_s[w][rq*8 + hi*4];
        float invs[4] = {1.f/lv.x, 1.f/lv.y, 1.f/lv.z, 1.f/lv.w};
        #pragma unroll
        for (int i = 0; i < 4; i++) {
            int sQ = q0 + rq*8 + hi*4 + i;
            size_t rowb = ((size_t)(n*1024 + sQ))*512 + h*64;
            ao[rowb + lq]      = (unsigned short)f2bf_rn(O0[rq*4+i] * invs[i]);
            ao[rowb + 32 + lq] = (unsigned short)f2bf_rn(O1[rq*4+i] * invs[i]);
        }
    }
}

// ---------------- out GEMM: D[s][d] = sum_c aoT[s][c]*WoT[d][c]; +bias+x ----------------
__global__ __launch_bounds__(256) void out_kernel(
        const unsigned short* __restrict__ aoT, const unsigned short* __restrict__ WoT,
        const float* __restrict__ bout, const float* __restrict__ x,
        float* __restrict__ out) {
    int s0 = blockIdx.x * 128, d0b = blockIdx.y * 128, n = blockIdx.z;
    __shared__ unsigned short At[4096];
    __shared__ unsigned short Bt[4096];
    int tid = threadIdx.x;
    int lane = tid & 63, w = tid >> 6;
    int quad = lane >> 4, tx = lane & 15;
    int moff = (w & 1) * 64, noff = (w >> 1) * 64;

    const unsigned short* Arow = aoT + ((size_t)n * 1024 + s0) * 512;
    const unsigned short* Brow = WoT + (size_t)d0b * 512;

    f32x4v acc[4][4];
    #pragma unroll
    for (int i = 0; i < 4; i++)
        #pragma unroll
        for (int j = 0; j < 4; j++)
            #pragma unroll
            for (int e = 0; e < 4; e++) acc[i][j][e] = 0.f;

    int f1 = tid, f2 = tid + 256;
    int m1 = f1 >> 2, kb1 = ((f1 & 3) - (f1 >> 3)) & 3;
    int m2 = f2 >> 2, kb2 = ((f2 & 3) - (f2 >> 3)) & 3;

    for (int k0 = 0; k0 < 512; k0 += 32) {
        __syncthreads();
        GLD_LDS16(Arow + (size_t)m1*512 + k0 + kb1*8, At + f1*8);
        GLD_LDS16(Arow + (size_t)m2*512 + k0 + kb2*8, At + f2*8);
        GLD_LDS16(Brow + (size_t)m1*512 + k0 + kb1*8, Bt + f1*8);
        GLD_LDS16(Brow + (size_t)m2*512 + k0 + kb2*8, Bt + f2*8);
        __syncthreads();
        bf16x8 af[4], bfr[4];
        #pragma unroll
        for (int mt = 0; mt < 4; mt++) {
            int m = moff + mt*16 + tx;
            int ch = m*4 + ((quad + (m >> 1)) & 3);
            af[mt] = *(const bf16x8*)(At + ch*8);
        }
        #pragma unroll
        for (int nt = 0; nt < 4; nt++) {
            int m = noff + nt*16 + tx;
            int ch = m*4 + ((quad + (m >> 1)) & 3);
            bfr[nt] = *(const bf16x8*)(Bt + ch*8);
        }
        #pragma unroll
        for (int mt = 0; mt < 4; mt++)
            #pragma unroll
            for (int nt = 0; nt < 4; nt++)
                acc[mt][nt] = __builtin_amdgcn_mfma_f32_16x16x32_bf16(
                    af[mt], bfr[nt], acc[mt][nt], 0, 0, 0);
    }

    #pragma unroll
    for (int mt = 0; mt < 4; mt++) {
        int sQ = s0 + moff + mt*16 + quad*4;
        #pragma unroll
        for (int nt = 0; nt < 4; nt++) {
            int d = d0b + noff + nt*16 + tx;
            float bo = bout[d];
            size_t base = ((size_t)n*512 + d)*1024 + sQ;
            float4 xv = *(const float4*)(x + base);
            f32x4v a = acc[mt][nt];
            float4 o = make_float4(a[0]+bo+xv.x, a[1]+bo+xv.y, a[2]+bo+xv.z, a[3]+bo+xv.w);
            *(float4*)(out + base) = o;
        }
    }
}

extern "C" void kernel_launch(void* const* d_in, const int* in_sizes, int n_in,
                              void* d_out, int out_size, void* d_ws, size_t ws_size,
                              hipStream_t stream) {
    const float* x    = (const float*)d_in[0];
    const float* gns  = (const float*)d_in[1];
    const float* gnb  = (const float*)d_in[2];
    const float* wqkv = (const float*)d_in[3];
    const float* bqkv = (const float*)d_in[4];
    const float* wout = (const float*)d_in[5];
    const float* bout = (const float*)d_in[6];
    float* out = (float*)d_out;

    char* p = (char*)d_ws;
    size_t off = 0;
    auto carve = [&](size_t bytes) {
        char* r = p + off;
        off = (off + bytes + 255) & ~(size_t)255;
        return r;
    };
    unsigned short* hnT = (unsigned short*)carve((size_t)16*1024*512*2);
    unsigned short* qb2 = (unsigned short*)carve((size_t)128*1024*64*2);
    unsigned short* kb2 = (unsigned short*)carve((size_t)128*1024*64*2);
    unsigned short* vb2 = (unsigned short*)carve((size_t)128*64*1024*2);
    unsigned short* aoT = (unsigned short*)carve((size_t)16*1024*512*2);
    unsigned short* WqT = (unsigned short*)carve((size_t)1536*512*2);
    unsigned short* WoT = (unsigned short*)carve((size_t)512*512*2);

    wt_kernel<<<dim3(64, 16), 256, 0, stream>>>(wqkv, wout, WqT, WoT);
    gn_kernel<<<dim3(512), 256, 0, stream>>>(x, gns, gnb, hnT);
    qkv_kernel<<<dim3(8, 12, 16), 256, 0, stream>>>(WqT, hnT, bqkv, qb2, kb2, vb2);
    attn_kernel<<<dim3(1024), 256, 0, stream>>>(qb2, kb2, vb2, aoT);
    out_kernel<<<dim3(8, 4, 16), 256, 0, stream>>>(aoT, WoT, bout, x, out);
}

// Round 4
// 246.125 us; speedup vs baseline: 4.1135x; 1.0079x over previous
//
#include <hip/hip_runtime.h>
#include <stdint.h>

typedef __bf16 bf16x8 __attribute__((ext_vector_type(8)));
typedef float f32x4v __attribute__((ext_vector_type(4)));
typedef float f32x16v __attribute__((ext_vector_type(16)));

// round-to-nearest bf16 (2 ops)
__device__ __forceinline__ unsigned f2bf_rn(float f) {
    return (__float_as_uint(f) + 0x8000u) >> 16;
}
// pack two floats -> two bf16 in one dword: 2 adds + 1 v_perm
__device__ __forceinline__ unsigned pk2bf(float a, float b) {
    return __builtin_amdgcn_perm(__float_as_uint(b) + 0x8000u,
                                 __float_as_uint(a) + 0x8000u, 0x07060302u);
}

#define GLD_LDS16(gp, lp) __builtin_amdgcn_global_load_lds( \
    (const __attribute__((address_space(1))) unsigned int*)(gp), \
    (__attribute__((address_space(3))) unsigned int*)(lp), 16, 0, 0)

// ---------------- weight transposes (both matrices, one launch) ----------------
__global__ __launch_bounds__(256) void wt_kernel(const float* __restrict__ wqkv,
        const float* __restrict__ wout, unsigned short* __restrict__ WqT,
        unsigned short* __restrict__ WoT) {
    __shared__ float tile[32][33];
    int bx = blockIdx.x;
    const float* in; unsigned short* out; int Cc, c0;
    if (bx < 48) { in = wqkv; out = WqT; Cc = 1536; c0 = bx * 32; }
    else         { in = wout; out = WoT; Cc = 512;  c0 = (bx - 48) * 32; }
    int r0 = blockIdx.y * 32;
    int tx = threadIdx.x & 31, ty = threadIdx.x >> 5;
    #pragma unroll
    for (int i = 0; i < 4; i++) {
        int r = ty + i * 8;
        tile[r][tx] = in[(size_t)(r0 + r) * Cc + c0 + tx];
    }
    __syncthreads();
    #pragma unroll
    for (int i = 0; i < 4; i++) {
        int cr = ty + i * 8;
        out[(size_t)(c0 + cr) * 512 + r0 + tx] = (unsigned short)f2bf_rn(tile[tx][cr]);
    }
}

// ---------------- GroupNorm -> hnT bf16 [n][s][c] ----------------
__global__ __launch_bounds__(256) void gn_kernel(const float* __restrict__ x,
        const float* __restrict__ scale, const float* __restrict__ bias,
        unsigned short* __restrict__ hnT) {
    int blk = blockIdx.x;                  // n*32+g
    int tid = threadIdx.x;
    int g = blk & 31, n = blk >> 5;
    const float4* src4 = (const float4*)(x + (size_t)blk * 16384);

    float s = 0.f, s2 = 0.f;
    for (int i = tid; i < 4096; i += 256) {
        float4 v = src4[i];
        s  += v.x + v.y + v.z + v.w;
        s2 += v.x*v.x + v.y*v.y + v.z*v.z + v.w*v.w;
    }
    __shared__ float red[256], red2[256];
    red[tid] = s; red2[tid] = s2;
    __syncthreads();
    for (int off = 128; off > 0; off >>= 1) {
        if (tid < off) { red[tid] += red[tid+off]; red2[tid] += red2[tid+off]; }
        __syncthreads();
    }
    __shared__ float sc_s[16], bi_s[16];
    if (tid < 16) {
        float mean = red[0] * (1.f/16384.f);
        float var  = red2[0] * (1.f/16384.f) - mean*mean;
        float rstd = rsqrtf(var + 1e-6f);
        int c = g*16 + tid;
        float sc = scale[c] * rstd;
        sc_s[tid] = sc;
        bi_s[tid] = bias[c] - mean * sc;
    }
    __shared__ float tile[16][260];
    for (int ch = 0; ch < 4; ch++) {
        __syncthreads();
        #pragma unroll
        for (int kk = 0; kk < 4; kk++) {
            int fi = tid + kk*256;
            int row = fi >> 6, col4 = fi & 63;
            float4 v = src4[row*256 + ch*64 + col4];
            *(float4*)&tile[row][col4*4] = v;
        }
        __syncthreads();
        int sQ = ch*256 + tid;
        unsigned int pk[8];
        #pragma unroll
        for (int c2 = 0; c2 < 8; c2++) {
            float a = tile[c2*2][tid]   * sc_s[c2*2]   + bi_s[c2*2];
            float b = tile[c2*2+1][tid] * sc_s[c2*2+1] + bi_s[c2*2+1];
            pk[c2] = pk2bf(a, b);
        }
        unsigned short* op = hnT + ((size_t)(n*1024 + sQ))*512 + g*16;
        *(uint4*)op       = make_uint4(pk[0], pk[1], pk[2], pk[3]);
        *((uint4*)op + 1) = make_uint4(pk[4], pk[5], pk[6], pk[7]);
    }
}

// ---------------- QKV GEMM: D[m][s] = sum_c WqT[m][c]*hnT[s][c] ----------------
__global__ __launch_bounds__(256) void qkv_kernel(
        const unsigned short* __restrict__ WqT, const unsigned short* __restrict__ hnT,
        const float* __restrict__ bqkv,
        unsigned short* __restrict__ qb, unsigned short* __restrict__ kbuf,
        unsigned short* __restrict__ vb) {
    int s0 = blockIdx.x * 128, m0 = blockIdx.y * 128, n = blockIdx.z;
    __shared__ unsigned short At[4096];    // 128 rows x 32 c, swizzled 16B chunks
    __shared__ unsigned short Bt[4096];
    int tid = threadIdx.x;
    int lane = tid & 63, w = tid >> 6;
    int quad = lane >> 4, tx = lane & 15;
    int moff = (w & 1) * 64, soff = (w >> 1) * 64;

    const unsigned short* Arow = WqT + (size_t)m0 * 512;
    const unsigned short* Brow = hnT + ((size_t)n * 1024 + s0) * 512;

    f32x4v acc[4][4];
    #pragma unroll
    for (int i = 0; i < 4; i++)
        #pragma unroll
        for (int j = 0; j < 4; j++)
            #pragma unroll
            for (int e = 0; e < 4; e++) acc[i][j][e] = 0.f;

    int f1 = tid, f2 = tid + 256;
    int m1 = f1 >> 2, kb1 = ((f1 & 3) - (f1 >> 3)) & 3;
    int m2 = f2 >> 2, kb2 = ((f2 & 3) - (f2 >> 3)) & 3;

    for (int k0 = 0; k0 < 512; k0 += 32) {
        __syncthreads();
        GLD_LDS16(Arow + (size_t)m1*512 + k0 + kb1*8, At + f1*8);
        GLD_LDS16(Arow + (size_t)m2*512 + k0 + kb2*8, At + f2*8);
        GLD_LDS16(Brow + (size_t)m1*512 + k0 + kb1*8, Bt + f1*8);
        GLD_LDS16(Brow + (size_t)m2*512 + k0 + kb2*8, Bt + f2*8);
        __syncthreads();
        bf16x8 af[4], bfr[4];
        #pragma unroll
        for (int mt = 0; mt < 4; mt++) {
            int m = moff + mt*16 + tx;
            int ch = m*4 + ((quad + (m >> 1)) & 3);
            af[mt] = *(const bf16x8*)(At + ch*8);
        }
        #pragma unroll
        for (int nt = 0; nt < 4; nt++) {
            int m = soff + nt*16 + tx;
            int ch = m*4 + ((quad + (m >> 1)) & 3);
            bfr[nt] = *(const bf16x8*)(Bt + ch*8);
        }
        #pragma unroll
        for (int mt = 0; mt < 4; mt++)
            #pragma unroll
            for (int nt = 0; nt < 4; nt++)
                acc[mt][nt] = __builtin_amdgcn_mfma_f32_16x16x32_bf16(
                    af[mt], bfr[nt], acc[mt][nt], 0, 0, 0);
    }

    // Epilogue: q scaled by 0.125*log2(e) (exp2-domain softmax downstream).
    const float QSCL = 0.18033688011112042f;
    #pragma unroll
    for (int mt = 0; mt < 4; mt++) {
        int m = m0 + moff + mt*16 + quad*4;
        int head = m / 192;
        int r = m - head*192;
        int which = r >> 6;
        int d0 = r & 63;
        float4 bia = *(const float4*)(bqkv + m);
        float scl = (which == 0) ? QSCL : 1.0f;
        #pragma unroll
        for (int nt = 0; nt < 4; nt++) {
            int sQ = s0 + soff + nt*16 + tx;
            f32x4v a = acc[mt][nt];
            float v0 = (a[0]+bia.x)*scl, v1 = (a[1]+bia.y)*scl;
            float v2 = (a[2]+bia.z)*scl, v3 = (a[3]+bia.w)*scl;
            if (which < 2) {
                unsigned short* base = (which == 0) ? qb : kbuf;
                unsigned lo = pk2bf(v0, v1), hi2 = pk2bf(v2, v3);
                *(uint2*)(base + (((size_t)(n*8 + head)*1024 + sQ) << 6) + d0) =
                    make_uint2(lo, hi2);
            } else {
                size_t vbase = ((size_t)(n*8 + head)*64 + d0)*1024 + sQ;
                vb[vbase]        = (unsigned short)f2bf_rn(v0);
                vb[vbase + 1024] = (unsigned short)f2bf_rn(v1);
                vb[vbase + 2048] = (unsigned short)f2bf_rn(v2);
                vb[vbase + 3072] = (unsigned short)f2bf_rn(v3);
            }
        }
    }
}

// ---------------- flash attention, BK=64, fixed-max exp2 softmax ----------------
// Logits are 0.18*(q.k) with normalized activations: |logit| << 127, so
// exp2 without max-subtraction cannot overflow; softmax is exact modulo rounding.
__global__ __launch_bounds__(256) void attn_kernel(
        const unsigned short* __restrict__ qg, const unsigned short* __restrict__ kg,
        const unsigned short* __restrict__ vg, unsigned short* __restrict__ ao) {
    int bid = blockIdx.x;
    int nh = bid & 127, qbk = bid >> 7;     // 8 q-blocks of one head share an XCD
    int tid = threadIdx.x, w = tid >> 6, lane = tid & 63;
    int lq = lane & 31, hi = lane >> 5;
    const unsigned short* Q = qg + (size_t)nh * 65536;
    const unsigned short* K = kg + (size_t)nh * 65536;
    const unsigned short* V = vg + (size_t)nh * 65536;   // [d][t]

    __shared__ unsigned short Klds[64*72];               // [t][d], pad 8
    __shared__ unsigned short Vlds[64*72];               // [d][t], pad 8
    __shared__ unsigned short Plds[4][32*72];            // per-wave [q][t], pad 8
    __shared__ float lsum_s[4][32];

    int q0 = qbk*128 + w*32;
    bf16x8 qf[4];
    #pragma unroll
    for (int ks = 0; ks < 4; ks++)
        qf[ks] = *(const bf16x8*)(Q + ((size_t)(q0 + lq))*64 + ks*16 + hi*8);

    f32x16v O0, O1;
    #pragma unroll
    for (int i = 0; i < 16; i++) { O0[i] = 0.f; O1[i] = 0.f; }
    float lsum = 0.f;

    for (int t0 = 0; t0 < 1024; t0 += 64) {
        __syncthreads();
        {   // stage K [64][64] and V [64][64] (V global is [d][t])
            int r = tid >> 2, part = (tid & 3) * 16;
            const uint4* kp = (const uint4*)(K + (size_t)(t0 + r)*64 + part);
            uint4 a = kp[0], b = kp[1];
            unsigned short* kd = Klds + r*72 + part;
            *(uint4*)kd = a; *(uint4*)(kd+8) = b;
            const uint4* vp = (const uint4*)(V + (size_t)r*1024 + t0 + part);
            uint4 c = vp[0], d = vp[1];
            unsigned short* vd = Vlds + r*72 + part;
            *(uint4*)vd = c; *(uint4*)(vd+8) = d;
        }
        __syncthreads();

        f32x16v S0, S1;
        #pragma unroll
        for (int i = 0; i < 16; i++) { S0[i] = 0.f; S1[i] = 0.f; }
        #pragma unroll
        for (int ks = 0; ks < 4; ks++) {
            bf16x8 a0 = *(const bf16x8*)(Klds + lq*72 + ks*16 + hi*8);
            bf16x8 a1 = *(const bf16x8*)(Klds + (32+lq)*72 + ks*16 + hi*8);
            S0 = __builtin_amdgcn_mfma_f32_32x32x16_bf16(a0, qf[ks], S0, 0, 0, 0);
            S1 = __builtin_amdgcn_mfma_f32_32x32x16_bf16(a1, qf[ks], S1, 0, 0, 0);
        }

        // p = exp2(S); accumulate per-lane partial l; pack to LDS [q][t]
        #pragma unroll
        for (int i = 0; i < 16; i++) {
            S0[i] = exp2f(S0[i]);
            S1[i] = exp2f(S1[i]);
            lsum += S0[i] + S1[i];
        }
        unsigned short* Pw = Plds[w];
        #pragma unroll
        for (int rq = 0; rq < 4; rq++) {
            unsigned a0 = pk2bf(S0[rq*4+0], S0[rq*4+1]);
            unsigned a1 = pk2bf(S0[rq*4+2], S0[rq*4+3]);
            unsigned b0 = pk2bf(S1[rq*4+0], S1[rq*4+1]);
            unsigned b1 = pk2bf(S1[rq*4+2], S1[rq*4+3]);
            *(uint2*)(Pw + lq*72 + rq*8 + hi*4)      = make_uint2(a0, a1);
            *(uint2*)(Pw + lq*72 + 32 + rq*8 + hi*4) = make_uint2(b0, b1);
        }

        #pragma unroll
        for (int ks = 0; ks < 4; ks++) {
            bf16x8 pa = *(const bf16x8*)(Pw + lq*72 + ks*16 + hi*8);
            bf16x8 v0 = *(const bf16x8*)(Vlds + lq*72 + ks*16 + hi*8);
            bf16x8 v1 = *(const bf16x8*)(Vlds + (32+lq)*72 + ks*16 + hi*8);
            O0 = __builtin_amdgcn_mfma_f32_32x32x16_bf16(pa, v0, O0, 0, 0, 0);
            O1 = __builtin_amdgcn_mfma_f32_32x32x16_bf16(pa, v1, O1, 0, 0, 0);
        }
    }

    lsum += __shfl_xor(lsum, 32);
    lsum_s[w][lq] = lsum;
    int n = nh >> 3, h = nh & 7;
    #pragma unroll
    for (int rq = 0; rq < 4; rq++) {
        float4 lv = *(const float4*)&lsum_s[w][rq*8 + hi*4];
        float invs[4] = {1.f/lv.x, 1.f/lv.y, 1.f/lv.z, 1.f/lv.w};
        #pragma unroll
        for (int i = 0; i < 4; i++) {
            int sQ = q0 + rq*8 + hi*4 + i;
            size_t rowb = ((size_t)(n*1024 + sQ))*512 + h*64;
            ao[rowb + lq]      = (unsigned short)f2bf_rn(O0[rq*4+i] * invs[i]);
            ao[rowb + 32 + lq] = (unsigned short)f2bf_rn(O1[rq*4+i] * invs[i]);
        }
    }
}

// ---------------- out GEMM: D[s][d] = sum_c aoT[s][c]*WoT[d][c]; +bias+x ----------------
__global__ __launch_bounds__(256) void out_kernel(
        const unsigned short* __restrict__ aoT, const unsigned short* __restrict__ WoT,
        const float* __restrict__ bout, const float* __restrict__ x,
        float* __restrict__ out) {
    int s0 = blockIdx.x * 128, d0b = blockIdx.y * 128, n = blockIdx.z;
    __shared__ unsigned short At[4096];
    __shared__ unsigned short Bt[4096];
    int tid = threadIdx.x;
    int lane = tid & 63, w = tid >> 6;
    int quad = lane >> 4, tx = lane & 15;
    int moff = (w & 1) * 64, noff = (w >> 1) * 64;

    const unsigned short* Arow = aoT + ((size_t)n * 1024 + s0) * 512;
    const unsigned short* Brow = WoT + (size_t)d0b * 512;

    f32x4v acc[4][4];
    #pragma unroll
    for (int i = 0; i < 4; i++)
        #pragma unroll
        for (int j = 0; j < 4; j++)
            #pragma unroll
            for (int e = 0; e < 4; e++) acc[i][j][e] = 0.f;

    int f1 = tid, f2 = tid + 256;
    int m1 = f1 >> 2, kb1 = ((f1 & 3) - (f1 >> 3)) & 3;
    int m2 = f2 >> 2, kb2 = ((f2 & 3) - (f2 >> 3)) & 3;

    for (int k0 = 0; k0 < 512; k0 += 32) {
        __syncthreads();
        GLD_LDS16(Arow + (size_t)m1*512 + k0 + kb1*8, At + f1*8);
        GLD_LDS16(Arow + (size_t)m2*512 + k0 + kb2*8, At + f2*8);
        GLD_LDS16(Brow + (size_t)m1*512 + k0 + kb1*8, Bt + f1*8);
        GLD_LDS16(Brow + (size_t)m2*512 + k0 + kb2*8, Bt + f2*8);
        __syncthreads();
        bf16x8 af[4], bfr[4];
        #pragma unroll
        for (int mt = 0; mt < 4; mt++) {
            int m = moff + mt*16 + tx;
            int ch = m*4 + ((quad + (m >> 1)) & 3);
            af[mt] = *(const bf16x8*)(At + ch*8);
        }
        #pragma unroll
        for (int nt = 0; nt < 4; nt++) {
            int m = noff + nt*16 + tx;
            int ch = m*4 + ((quad + (m >> 1)) & 3);
            bfr[nt] = *(const bf16x8*)(Bt + ch*8);
        }
        #pragma unroll
        for (int mt = 0; mt < 4; mt++)
            #pragma unroll
            for (int nt = 0; nt < 4; nt++)
                acc[mt][nt] = __builtin_amdgcn_mfma_f32_16x16x32_bf16(
                    af[mt], bfr[nt], acc[mt][nt], 0, 0, 0);
    }

    #pragma unroll
    for (int mt = 0; mt < 4; mt++) {
        int sQ = s0 + moff + mt*16 + quad*4;
        #pragma unroll
        for (int nt = 0; nt < 4; nt++) {
            int d = d0b + noff + nt*16 + tx;
            float bo = bout[d];
            size_t base = ((size_t)n*512 + d)*1024 + sQ;
            float4 xv = *(const float4*)(x + base);
            f32x4v a = acc[mt][nt];
            float4 o = make_float4(a[0]+bo+xv.x, a[1]+bo+xv.y, a[2]+bo+xv.z, a[3]+bo+xv.w);
            *(float4*)(out + base) = o;
        }
    }
}

extern "C" void kernel_launch(void* const* d_in, const int* in_sizes, int n_in,
                              void* d_out, int out_size, void* d_ws, size_t ws_size,
                              hipStream_t stream) {
    const float* x    = (const float*)d_in[0];
    const float* gns  = (const float*)d_in[1];
    const float* gnb  = (const float*)d_in[2];
    const float* wqkv = (const float*)d_in[3];
    const float* bqkv = (const float*)d_in[4];
    const float* wout = (const float*)d_in[5];
    const float* bout = (const float*)d_in[6];
    float* out = (float*)d_out;

    char* p = (char*)d_ws;
    size_t off = 0;
    auto carve = [&](size_t bytes) {
        char* r = p + off;
        off = (off + bytes + 255) & ~(size_t)255;
        return r;
    };
    unsigned short* hnT = (unsigned short*)carve((size_t)16*1024*512*2);
    unsigned short* qb2 = (unsigned short*)carve((size_t)128*1024*64*2);
    unsigned short* kb2 = (unsigned short*)carve((size_t)128*1024*64*2);
    unsigned short* vb2 = (unsigned short*)carve((size_t)128*64*1024*2);
    unsigned short* aoT = (unsigned short*)carve((size_t)16*1024*512*2);
    unsigned short* WqT = (unsigned short*)carve((size_t)1536*512*2);
    unsigned short* WoT = (unsigned short*)carve((size_t)512*512*2);

    wt_kernel<<<dim3(64, 16), 256, 0, stream>>>(wqkv, wout, WqT, WoT);
    gn_kernel<<<dim3(512), 256, 0, stream>>>(x, gns, gnb, hnT);
    qkv_kernel<<<dim3(8, 12, 16), 256, 0, stream>>>(WqT, hnT, bqkv, qb2, kb2, vb2);
    attn_kernel<<<dim3(1024), 256, 0, stream>>>(qb2, kb2, vb2, aoT);
    out_kernel<<<dim3(8, 4, 16), 256, 0, stream>>>(aoT, WoT, bout, x, out);
}

// Round 5
// 238.776 us; speedup vs baseline: 4.2401x; 1.0308x over previous
//
#include <hip/hip_runtime.h>
#include <stdint.h>

typedef __bf16 bf16x8 __attribute__((ext_vector_type(8)));
typedef float f32x4v __attribute__((ext_vector_type(4)));
typedef float f32x16v __attribute__((ext_vector_type(16)));
typedef unsigned u32x2 __attribute__((ext_vector_type(2)));

// round-to-nearest bf16 (2 ops)
__device__ __forceinline__ unsigned f2bf_rn(float f) {
    return (__float_as_uint(f) + 0x8000u) >> 16;
}
// pack two floats -> two bf16 in one dword: 2 adds + 1 v_perm
__device__ __forceinline__ unsigned pk2bf(float a, float b) {
    return __builtin_amdgcn_perm(__float_as_uint(b) + 0x8000u,
                                 __float_as_uint(a) + 0x8000u, 0x07060302u);
}

// swap a.hi32lanes <-> b.lo32lanes (gfx950 v_permlane32_swap_b32)
__device__ __forceinline__ void swap32(unsigned &a, unsigned &b) {
#if __has_builtin(__builtin_amdgcn_permlane32_swap)
    u32x2 r = __builtin_amdgcn_permlane32_swap(a, b, false, false);
    a = r[0]; b = r[1];
#else
    unsigned pa = (unsigned)__shfl_xor((int)a, 32);
    unsigned pb = (unsigned)__shfl_xor((int)b, 32);
    bool hi = (threadIdx.x & 32) != 0;
    unsigned na = hi ? pb : a;
    unsigned nb = hi ? b : pa;
    a = na; b = nb;
#endif
}

__device__ __forceinline__ bf16x8 mk8(unsigned a, unsigned b, unsigned c, unsigned e) {
    union { int4 i; bf16x8 v; } u;
    u.i = make_int4((int)a, (int)b, (int)c, (int)e);
    return u.v;
}

#define GLD_LDS16(gp, lp) __builtin_amdgcn_global_load_lds( \
    (const __attribute__((address_space(1))) unsigned int*)(gp), \
    (__attribute__((address_space(3))) unsigned int*)(lp), 16, 0, 0)

// ---------------- weight transposes (both matrices, one launch) ----------------
__global__ __launch_bounds__(256) void wt_kernel(const float* __restrict__ wqkv,
        const float* __restrict__ wout, unsigned short* __restrict__ WqT,
        unsigned short* __restrict__ WoT) {
    __shared__ float tile[32][33];
    int bx = blockIdx.x;
    const float* in; unsigned short* out; int Cc, c0;
    if (bx < 48) { in = wqkv; out = WqT; Cc = 1536; c0 = bx * 32; }
    else         { in = wout; out = WoT; Cc = 512;  c0 = (bx - 48) * 32; }
    int r0 = blockIdx.y * 32;
    int tx = threadIdx.x & 31, ty = threadIdx.x >> 5;
    #pragma unroll
    for (int i = 0; i < 4; i++) {
        int r = ty + i * 8;
        tile[r][tx] = in[(size_t)(r0 + r) * Cc + c0 + tx];
    }
    __syncthreads();
    #pragma unroll
    for (int i = 0; i < 4; i++) {
        int cr = ty + i * 8;
        out[(size_t)(c0 + cr) * 512 + r0 + tx] = (unsigned short)f2bf_rn(tile[tx][cr]);
    }
}

// ---------------- GroupNorm -> hnT bf16 [n][s][c] ----------------
__global__ __launch_bounds__(256) void gn_kernel(const float* __restrict__ x,
        const float* __restrict__ scale, const float* __restrict__ bias,
        unsigned short* __restrict__ hnT) {
    int blk = blockIdx.x;                  // n*32+g
    int tid = threadIdx.x;
    int g = blk & 31, n = blk >> 5;
    const float4* src4 = (const float4*)(x + (size_t)blk * 16384);

    float s = 0.f, s2 = 0.f;
    for (int i = tid; i < 4096; i += 256) {
        float4 v = src4[i];
        s  += v.x + v.y + v.z + v.w;
        s2 += v.x*v.x + v.y*v.y + v.z*v.z + v.w*v.w;
    }
    __shared__ float red[256], red2[256];
    red[tid] = s; red2[tid] = s2;
    __syncthreads();
    for (int off = 128; off > 0; off >>= 1) {
        if (tid < off) { red[tid] += red[tid+off]; red2[tid] += red2[tid+off]; }
        __syncthreads();
    }
    __shared__ float sc_s[16], bi_s[16];
    if (tid < 16) {
        float mean = red[0] * (1.f/16384.f);
        float var  = red2[0] * (1.f/16384.f) - mean*mean;
        float rstd = rsqrtf(var + 1e-6f);
        int c = g*16 + tid;
        float sc = scale[c] * rstd;
        sc_s[tid] = sc;
        bi_s[tid] = bias[c] - mean * sc;
    }
    __shared__ float tile[16][260];
    for (int ch = 0; ch < 4; ch++) {
        __syncthreads();
        #pragma unroll
        for (int kk = 0; kk < 4; kk++) {
            int fi = tid + kk*256;
            int row = fi >> 6, col4 = fi & 63;
            float4 v = src4[row*256 + ch*64 + col4];
            *(float4*)&tile[row][col4*4] = v;
        }
        __syncthreads();
        int sQ = ch*256 + tid;
        unsigned int pk[8];
        #pragma unroll
        for (int c2 = 0; c2 < 8; c2++) {
            float a = tile[c2*2][tid]   * sc_s[c2*2]   + bi_s[c2*2];
            float b = tile[c2*2+1][tid] * sc_s[c2*2+1] + bi_s[c2*2+1];
            pk[c2] = pk2bf(a, b);
        }
        unsigned short* op = hnT + ((size_t)(n*1024 + sQ))*512 + g*16;
        *(uint4*)op       = make_uint4(pk[0], pk[1], pk[2], pk[3]);
        *((uint4*)op + 1) = make_uint4(pk[4], pk[5], pk[6], pk[7]);
    }
}

// ---------------- QKV GEMM: D[m][s] = sum_c WqT[m][c]*hnT[s][c] ----------------
__global__ __launch_bounds__(256) void qkv_kernel(
        const unsigned short* __restrict__ WqT, const unsigned short* __restrict__ hnT,
        const float* __restrict__ bqkv,
        unsigned short* __restrict__ qb, unsigned short* __restrict__ kbuf,
        unsigned short* __restrict__ vb) {
    int s0 = blockIdx.x * 128, m0 = blockIdx.y * 128, n = blockIdx.z;
    __shared__ unsigned short At[4096];    // 128 rows x 32 c, swizzled 16B chunks
    __shared__ unsigned short Bt[4096];
    int tid = threadIdx.x;
    int lane = tid & 63, w = tid >> 6;
    int quad = lane >> 4, tx = lane & 15;
    int moff = (w & 1) * 64, soff = (w >> 1) * 64;

    const unsigned short* Arow = WqT + (size_t)m0 * 512;
    const unsigned short* Brow = hnT + ((size_t)n * 1024 + s0) * 512;

    f32x4v acc[4][4];
    #pragma unroll
    for (int i = 0; i < 4; i++)
        #pragma unroll
        for (int j = 0; j < 4; j++)
            #pragma unroll
            for (int e = 0; e < 4; e++) acc[i][j][e] = 0.f;

    int f1 = tid, f2 = tid + 256;
    int m1 = f1 >> 2, kb1 = ((f1 & 3) - (f1 >> 3)) & 3;
    int m2 = f2 >> 2, kb2 = ((f2 & 3) - (f2 >> 3)) & 3;

    for (int k0 = 0; k0 < 512; k0 += 32) {
        __syncthreads();
        GLD_LDS16(Arow + (size_t)m1*512 + k0 + kb1*8, At + f1*8);
        GLD_LDS16(Arow + (size_t)m2*512 + k0 + kb2*8, At + f2*8);
        GLD_LDS16(Brow + (size_t)m1*512 + k0 + kb1*8, Bt + f1*8);
        GLD_LDS16(Brow + (size_t)m2*512 + k0 + kb2*8, Bt + f2*8);
        __syncthreads();
        bf16x8 af[4], bfr[4];
        #pragma unroll
        for (int mt = 0; mt < 4; mt++) {
            int m = moff + mt*16 + tx;
            int ch = m*4 + ((quad + (m >> 1)) & 3);
            af[mt] = *(const bf16x8*)(At + ch*8);
        }
        #pragma unroll
        for (int nt = 0; nt < 4; nt++) {
            int m = soff + nt*16 + tx;
            int ch = m*4 + ((quad + (m >> 1)) & 3);
            bfr[nt] = *(const bf16x8*)(Bt + ch*8);
        }
        #pragma unroll
        for (int mt = 0; mt < 4; mt++)
            #pragma unroll
            for (int nt = 0; nt < 4; nt++)
                acc[mt][nt] = __builtin_amdgcn_mfma_f32_16x16x32_bf16(
                    af[mt], bfr[nt], acc[mt][nt], 0, 0, 0);
    }

    // Epilogue: q scaled by 0.125*log2(e) (exp2-domain softmax downstream).
    const float QSCL = 0.18033688011112042f;
    #pragma unroll
    for (int mt = 0; mt < 4; mt++) {
        int m = m0 + moff + mt*16 + quad*4;
        int head = m / 192;
        int r = m - head*192;
        int which = r >> 6;
        int d0 = r & 63;
        float4 bia = *(const float4*)(bqkv + m);
        float scl = (which == 0) ? QSCL : 1.0f;
        #pragma unroll
        for (int nt = 0; nt < 4; nt++) {
            int sQ = s0 + soff + nt*16 + tx;
            f32x4v a = acc[mt][nt];
            float v0 = (a[0]+bia.x)*scl, v1 = (a[1]+bia.y)*scl;
            float v2 = (a[2]+bia.z)*scl, v3 = (a[3]+bia.w)*scl;
            if (which < 2) {
                unsigned short* base = (which == 0) ? qb : kbuf;
                unsigned lo = pk2bf(v0, v1), hi2 = pk2bf(v2, v3);
                *(uint2*)(base + (((size_t)(n*8 + head)*1024 + sQ) << 6) + d0) =
                    make_uint2(lo, hi2);
            } else {
                size_t vbase = ((size_t)(n*8 + head)*64 + d0)*1024 + sQ;
                vb[vbase]        = (unsigned short)f2bf_rn(v0);
                vb[vbase + 1024] = (unsigned short)f2bf_rn(v1);
                vb[vbase + 2048] = (unsigned short)f2bf_rn(v2);
                vb[vbase + 3072] = (unsigned short)f2bf_rn(v3);
            }
        }
    }
}

// ---------------- flash attention: in-register P transpose, pipelined staging ----
// Fixed-max exp2 softmax (logits are 0.18*(q.k), |logit| << 127 so no overflow).
// S^T = K*Q^T gives C-layout col=q, row=t; 4 permlane32_swap per 32-t block
// converts packed P dwords directly to the PV A-operand layout (no LDS trip).
__global__ __launch_bounds__(256) void attn_kernel(
        const unsigned short* __restrict__ qg, const unsigned short* __restrict__ kg,
        const unsigned short* __restrict__ vg, unsigned short* __restrict__ ao) {
    int bid = blockIdx.x;
    int nh = bid & 127, qbk = bid >> 7;     // 8 q-blocks of one head share an XCD
    int tid = threadIdx.x, w = tid >> 6, lane = tid & 63;
    int lq = lane & 31, hi = lane >> 5;
    const unsigned short* Q = qg + (size_t)nh * 65536;
    const unsigned short* K = kg + (size_t)nh * 65536;
    const unsigned short* V = vg + (size_t)nh * 65536;   // [d][t]

    __shared__ unsigned short Klds[2][64*72];            // [t][d], pad 8
    __shared__ unsigned short Vlds[2][64*72];            // [d][t], pad 8
    __shared__ float lsum_s[4][32];

    int q0 = qbk*128 + w*32;
    bf16x8 qf[4];
    #pragma unroll
    for (int ks = 0; ks < 4; ks++)
        qf[ks] = *(const bf16x8*)(Q + ((size_t)(q0 + lq))*64 + ks*16 + hi*8);

    // staging: each thread owns 32B of K-tile and V-tile
    int r = tid >> 2, part = (tid & 3) * 16;
    uint4 ka, kb2, va, vb2;
    ka  = *(const uint4*)(K + (size_t)r*64 + part);
    kb2 = *(const uint4*)(K + (size_t)r*64 + part + 8);
    va  = *(const uint4*)(V + (size_t)r*1024 + part);
    vb2 = *(const uint4*)(V + (size_t)r*1024 + part + 8);

    f32x16v O0, O1;
    #pragma unroll
    for (int i = 0; i < 16; i++) { O0[i] = 0.f; O1[i] = 0.f; }
    float lsum = 0.f;

    for (int it = 0; it < 16; it++) {
        int buf = it & 1;
        {   // commit staged regs to LDS
            unsigned short* kd = Klds[buf] + r*72 + part;
            *(uint4*)kd = ka; *(uint4*)(kd+8) = kb2;
            unsigned short* vd = Vlds[buf] + r*72 + part;
            *(uint4*)vd = va; *(uint4*)(vd+8) = vb2;
        }
        __syncthreads();
        if (it < 15) {   // prefetch next tile (overlaps compute below)
            int t0 = (it + 1) * 64;
            ka  = *(const uint4*)(K + (size_t)(t0 + r)*64 + part);
            kb2 = *(const uint4*)(K + (size_t)(t0 + r)*64 + part + 8);
            va  = *(const uint4*)(V + (size_t)r*1024 + t0 + part);
            vb2 = *(const uint4*)(V + (size_t)r*1024 + t0 + part + 8);
        }
        const unsigned short* Kb = Klds[buf];
        const unsigned short* Vb = Vlds[buf];

        f32x16v S0, S1;
        #pragma unroll
        for (int i = 0; i < 16; i++) { S0[i] = 0.f; S1[i] = 0.f; }
        #pragma unroll
        for (int ks = 0; ks < 4; ks++) {
            bf16x8 a0 = *(const bf16x8*)(Kb + lq*72 + ks*16 + hi*8);
            bf16x8 a1 = *(const bf16x8*)(Kb + (32+lq)*72 + ks*16 + hi*8);
            S0 = __builtin_amdgcn_mfma_f32_32x32x16_bf16(a0, qf[ks], S0, 0, 0, 0);
            S1 = __builtin_amdgcn_mfma_f32_32x32x16_bf16(a1, qf[ks], S1, 0, 0, 0);
        }

        // p = exp2(S); per-lane partial l; pack reg pairs into dwords
        #pragma unroll
        for (int i = 0; i < 16; i++) {
            S0[i] = exp2f(S0[i]);
            S1[i] = exp2f(S1[i]);
            lsum += S0[i] + S1[i];
        }
        unsigned d[16];
        #pragma unroll
        for (int p2 = 0; p2 < 8; p2++) {
            d[p2]     = pk2bf(S0[p2*2], S0[p2*2+1]);
            d[8 + p2] = pk2bf(S1[p2*2], S1[p2*2+1]);
        }
        // in-register C->A transform: swap(d0,d2)->(A0,A2), swap(d1,d3)->(A1,A3)
        swap32(d[0],  d[2]);  swap32(d[1],  d[3]);
        swap32(d[4],  d[6]);  swap32(d[5],  d[7]);
        swap32(d[8],  d[10]); swap32(d[9],  d[11]);
        swap32(d[12], d[14]); swap32(d[13], d[15]);

        #pragma unroll
        for (int kc = 0; kc < 4; kc++) {
            bf16x8 pa = mk8(d[kc*4+0], d[kc*4+1], d[kc*4+2], d[kc*4+3]);
            bf16x8 v0 = *(const bf16x8*)(Vb + lq*72 + kc*16 + hi*8);
            bf16x8 v1 = *(const bf16x8*)(Vb + (32+lq)*72 + kc*16 + hi*8);
            O0 = __builtin_amdgcn_mfma_f32_32x32x16_bf16(pa, v0, O0, 0, 0, 0);
            O1 = __builtin_amdgcn_mfma_f32_32x32x16_bf16(pa, v1, O1, 0, 0, 0);
        }
    }

    lsum += __shfl_xor(lsum, 32);
    lsum_s[w][lq] = lsum;
    int n = nh >> 3, h = nh & 7;
    #pragma unroll
    for (int rq = 0; rq < 4; rq++) {
        float4 lv = *(const float4*)&lsum_s[w][rq*8 + hi*4];
        float invs[4] = {1.f/lv.x, 1.f/lv.y, 1.f/lv.z, 1.f/lv.w};
        #pragma unroll
        for (int i = 0; i < 4; i++) {
            int sQ = q0 + rq*8 + hi*4 + i;
            size_t rowb = ((size_t)(n*1024 + sQ))*512 + h*64;
            ao[rowb + lq]      = (unsigned short)f2bf_rn(O0[rq*4+i] * invs[i]);
            ao[rowb + 32 + lq] = (unsigned short)f2bf_rn(O1[rq*4+i] * invs[i]);
        }
    }
}

// ---------------- out GEMM: D[s][d] = sum_c aoT[s][c]*WoT[d][c]; +bias+x ----------------
__global__ __launch_bounds__(256) void out_kernel(
        const unsigned short* __restrict__ aoT, const unsigned short* __restrict__ WoT,
        const float* __restrict__ bout, const float* __restrict__ x,
        float* __restrict__ out) {
    int s0 = blockIdx.x * 128, d0b = blockIdx.y * 128, n = blockIdx.z;
    __shared__ unsigned short At[4096];
    __shared__ unsigned short Bt[4096];
    int tid = threadIdx.x;
    int lane = tid & 63, w = tid >> 6;
    int quad = lane >> 4, tx = lane & 15;
    int moff = (w & 1) * 64, noff = (w >> 1) * 64;

    const unsigned short* Arow = aoT + ((size_t)n * 1024 + s0) * 512;
    const unsigned short* Brow = WoT + (size_t)d0b * 512;

    f32x4v acc[4][4];
    #pragma unroll
    for (int i = 0; i < 4; i++)
        #pragma unroll
        for (int j = 0; j < 4; j++)
            #pragma unroll
            for (int e = 0; e < 4; e++) acc[i][j][e] = 0.f;

    int f1 = tid, f2 = tid + 256;
    int m1 = f1 >> 2, kb1 = ((f1 & 3) - (f1 >> 3)) & 3;
    int m2 = f2 >> 2, kb2 = ((f2 & 3) - (f2 >> 3)) & 3;

    for (int k0 = 0; k0 < 512; k0 += 32) {
        __syncthreads();
        GLD_LDS16(Arow + (size_t)m1*512 + k0 + kb1*8, At + f1*8);
        GLD_LDS16(Arow + (size_t)m2*512 + k0 + kb2*8, At + f2*8);
        GLD_LDS16(Brow + (size_t)m1*512 + k0 + kb1*8, Bt + f1*8);
        GLD_LDS16(Brow + (size_t)m2*512 + k0 + kb2*8, Bt + f2*8);
        __syncthreads();
        bf16x8 af[4], bfr[4];
        #pragma unroll
        for (int mt = 0; mt < 4; mt++) {
            int m = moff + mt*16 + tx;
            int ch = m*4 + ((quad + (m >> 1)) & 3);
            af[mt] = *(const bf16x8*)(At + ch*8);
        }
        #pragma unroll
        for (int nt = 0; nt < 4; nt++) {
            int m = noff + nt*16 + tx;
            int ch = m*4 + ((quad + (m >> 1)) & 3);
            bfr[nt] = *(const bf16x8*)(Bt + ch*8);
        }
        #pragma unroll
        for (int mt = 0; mt < 4; mt++)
            #pragma unroll
            for (int nt = 0; nt < 4; nt++)
                acc[mt][nt] = __builtin_amdgcn_mfma_f32_16x16x32_bf16(
                    af[mt], bfr[nt], acc[mt][nt], 0, 0, 0);
    }

    #pragma unroll
    for (int mt = 0; mt < 4; mt++) {
        int sQ = s0 + moff + mt*16 + quad*4;
        #pragma unroll
        for (int nt = 0; nt < 4; nt++) {
            int d = d0b + noff + nt*16 + tx;
            float bo = bout[d];
            size_t base = ((size_t)n*512 + d)*1024 + sQ;
            float4 xv = *(const float4*)(x + base);
            f32x4v a = acc[mt][nt];
            float4 o = make_float4(a[0]+bo+xv.x, a[1]+bo+xv.y, a[2]+bo+xv.z, a[3]+bo+xv.w);
            *(float4*)(out + base) = o;
        }
    }
}

extern "C" void kernel_launch(void* const* d_in, const int* in_sizes, int n_in,
                              void* d_out, int out_size, void* d_ws, size_t ws_size,
                              hipStream_t stream) {
    const float* x    = (const float*)d_in[0];
    const float* gns  = (const float*)d_in[1];
    const float* gnb  = (const float*)d_in[2];
    const float* wqkv = (const float*)d_in[3];
    const float* bqkv = (const float*)d_in[4];
    const float* wout = (const float*)d_in[5];
    const float* bout = (const float*)d_in[6];
    float* out = (float*)d_out;

    char* p = (char*)d_ws;
    size_t off = 0;
    auto carve = [&](size_t bytes) {
        char* r = p + off;
        off = (off + bytes + 255) & ~(size_t)255;
        return r;
    };
    unsigned short* hnT = (unsigned short*)carve((size_t)16*1024*512*2);
    unsigned short* qb2 = (unsigned short*)carve((size_t)128*1024*64*2);
    unsigned short* kb2 = (unsigned short*)carve((size_t)128*1024*64*2);
    unsigned short* vb2 = (unsigned short*)carve((size_t)128*64*1024*2);
    unsigned short* aoT = (unsigned short*)carve((size_t)16*1024*512*2);
    unsigned short* WqT = (unsigned short*)carve((size_t)1536*512*2);
    unsigned short* WoT = (unsigned short*)carve((size_t)512*512*2);

    wt_kernel<<<dim3(64, 16), 256, 0, stream>>>(wqkv, wout, WqT, WoT);
    gn_kernel<<<dim3(512), 256, 0, stream>>>(x, gns, gnb, hnT);
    qkv_kernel<<<dim3(8, 12, 16), 256, 0, stream>>>(WqT, hnT, bqkv, qb2, kb2, vb2);
    attn_kernel<<<dim3(1024), 256, 0, stream>>>(qb2, kb2, vb2, aoT);
    out_kernel<<<dim3(8, 4, 16), 256, 0, stream>>>(aoT, WoT, bout, x, out);
}